// Round 1
// baseline (304.318 us; speedup 1.0000x reference)
//
#include <hip/hip_runtime.h>
#include <math.h>

#ifndef M_PI
#define M_PI 3.14159265358979323846
#endif

#define BB 8
#define NN 512
#define KK 64
#define GG 4096
#define MM 100

// ---------------- workspace layout (byte offsets) ----------------
#define SZ_VD    (BB*GG*8u)
#define OFF_VD   0u
#define SZ_VM    (BB*MM*8u)
#define OFF_VM   (OFF_VD + SZ_VD)
#define SZ_AD    (BB*MM*MM*8u)
#define OFF_AD   (OFF_VM + SZ_VM)
#define OFF_MIND (OFF_AD + SZ_AD)

// ---------------- output layout (float element offsets) ----------------
#define OUT_M  0
#define OUT_V  (BB*NN*GG)               // 16,777,216
#define OUT_A  (OUT_V + BB*GG)          // 16,809,984
#define OUT_B  (OUT_A + BB*MM*MM)      // 16,889,984
#define OUT_MI (OUT_B + BB*MM*MM)      // 16,969,984

// ---------------- fast wave64 argmax (value, first-index) ----------------
#if __has_builtin(__builtin_amdgcn_update_dpp)
#define HAVE_DPP 1
#endif

__device__ __forceinline__ void wave_argmax(double v, int idx, double& out_v, int& out_i) {
#ifdef HAVE_DPP
#define DPPSTEP(CTRL) { \
    unsigned long long b = (unsigned long long)__double_as_longlong(v); \
    int slo = (int)(unsigned)(b & 0xffffffffull); \
    int shi = (int)(unsigned)(b >> 32); \
    unsigned lo = (unsigned)__builtin_amdgcn_update_dpp(slo, slo, CTRL, 0xf, 0xf, false); \
    unsigned hi = (unsigned)__builtin_amdgcn_update_dpp(shi, shi, CTRL, 0xf, 0xf, false); \
    double ov = __longlong_as_double((long long)(((unsigned long long)hi << 32) | lo)); \
    int oi = __builtin_amdgcn_update_dpp(idx, idx, CTRL, 0xf, 0xf, false); \
    if (ov > v || (ov == v && oi < idx)) { v = ov; idx = oi; } }
  DPPSTEP(0x111)  // row_shr:1
  DPPSTEP(0x112)  // row_shr:2
  DPPSTEP(0x114)  // row_shr:4
  DPPSTEP(0x118)  // row_shr:8
  DPPSTEP(0x142)  // row_bcast:15
  DPPSTEP(0x143)  // row_bcast:31
#undef DPPSTEP
  {
    unsigned long long b = (unsigned long long)__double_as_longlong(v);
    unsigned lo = (unsigned)__builtin_amdgcn_readlane((int)(unsigned)(b & 0xffffffffull), 63);
    unsigned hi = (unsigned)__builtin_amdgcn_readlane((int)(unsigned)(b >> 32), 63);
    out_v = __longlong_as_double((long long)(((unsigned long long)hi << 32) | lo));
    out_i = __builtin_amdgcn_readlane(idx, 63);
  }
#else
  for (int off = 32; off; off >>= 1) {
    double ov = __shfl_down(v, off);
    int oi = __shfl_down(idx, off);
    if (ov > v || (ov == v && oi < idx)) { v = ov; idx = oi; }
  }
  out_v = __shfl(v, 0); out_i = __shfl(idx, 0);
#endif
}

__device__ __forceinline__ double dbl_readlane(double v, int l) {
  long long b = __double_as_longlong(v);
  int lo = __builtin_amdgcn_readlane((int)(unsigned)((unsigned long long)b & 0xffffffffull), l);
  int hi = __builtin_amdgcn_readlane((int)(unsigned)((unsigned long long)b >> 32), l);
  return __longlong_as_double((long long)(((unsigned long long)(unsigned)hi << 32) | (unsigned)lo));
}

// ============ K2: v — two 64x64 matmuls, FULL-K, exp tables computed ON THE FLY ============
__global__ __launch_bounds__(256) void k_vpart(const float* __restrict__ pts,
                                               double* __restrict__ vd) {
  __shared__ double sEy2[16][66], sEx2[16][66], sEy3[16][66], sEx3[16][66];
  __shared__ float px[NN], py[NN];
  int bid = blockIdx.x;                 // img*16 + tile
  int tile = bid & 15;
  int img = bid >> 4;
  int iy0 = (tile >> 2) << 4;
  int ix0 = (tile & 3) << 4;
  int tx = threadIdx.x & 15, ty = threadIdx.x >> 4;
  for (int s = threadIdx.x; s < NN; s += 256) {
    px[s] = pts[(img*NN + s)*2 + 0];
    py[s] = pts[(img*NN + s)*2 + 1];
  }
  double aV = 0.0, aM = 0.0;
  for (int kc = 0; kc < 8; ++kc) {
    int nb = kc << 6;
    __syncthreads();                    // WAR on LDS (and px/py ready on kc=0)
    for (int s = threadIdx.x; s < 16*64; s += 256) {
      int row = s >> 6, n = s & 63;
      int nn = nb + n;
      double y = (double)py[nn];
      double cy = 8.0*(iy0 + row) + 4.0;
      double dy = y - cy, dy2 = dy*dy;
      sEy2[row][n] = exp(dy2*(-0.5/96.0));
      sEy3[row][n] = exp(dy2*(-1.0/128.0));
      double x = (double)px[nn];
      double cx = 8.0*(ix0 + row) + 4.0;
      double dx = x - cx, dx2 = dx*dx;
      sEx2[row][n] = exp(dx2*(-0.5/96.0));
      sEx3[row][n] = exp(dx2*(-1.0/128.0));
    }
    __syncthreads();
    #pragma unroll 8
    for (int n = 0; n < 64; ++n) {
      aV += sEy2[ty][n]*sEx2[tx][n];
      aM += sEy3[ty][n]*sEx3[tx][n];
    }
  }
  const double CTV = 1.0/((2.0*M_PI*96.0)*(2.0*M_PI*128.0));
  const double CM2 = 1.0/((2.0*M_PI*128.0)*(2.0*M_PI*128.0));
  vd[img*GG + (iy0 + ty)*KK + ix0 + tx] = CTV*aV - CM2*aM;
}

// ============ K3: top-100 select + v output — SINGLE-WAVE, BARRIER-FREE loop ============
__global__ __launch_bounds__(256) void k_select(const double* __restrict__ vd,
                                                float* __restrict__ out,
                                                int* __restrict__ minds,
                                                double* __restrict__ vm) {
  __shared__ double sv[GG + 64];        // padded: g -> g + (g>>6)  (rescan conflict-free)
  __shared__ int selbuf[MM];
  __shared__ int sidx[128];
  int img = blockIdx.x;
  int tid = threadIdx.x;
  for (int s = tid; s < GG; s += 256) {
    double v = vd[img*GG + s];
    sv[s + (s >> 6)] = v;
    out[OUT_V + img*GG + s] = (float)fmax(v, 1e-6);
  }
  __syncthreads();
  if (tid < 64) {
    int lane = tid;
    volatile double* svv = sv;
    double bv = -1e300; int gi = lane;
    #pragma unroll 8
    for (int c = 0; c < 64; ++c) {
      int g = c*64 + lane;
      double v = sv[g + c];             // g>>6 == c
      if (v > bv) { bv = v; gi = g; }
    }
    for (int r = 0; r < MM; ++r) {
      double gv; int gidx;
      wave_argmax(bv, gi, gv, gidx);
      if (lane == 0) selbuf[r] = gidx;
      int owner = gidx & 63;
      if (lane == owner) svv[gidx + (gidx >> 6)] = -1e300;
      int g2 = lane*64 + owner;         // c = lane
      double nv = svv[g2 + lane];       // g2>>6 == lane
      double nbv; int ngi;
      wave_argmax(nv, g2, nbv, ngi);
      if (lane == owner) { bv = nbv; gi = ngi; }
    }
  }
  __syncthreads();
  // sort the 100 selected indices ascending (bitonic over 128)
  if (tid < 128) sidx[tid] = (tid < MM) ? selbuf[tid] : 0x7fffffff;
  __syncthreads();
  for (int kk = 2; kk <= 128; kk <<= 1)
    for (int jj = kk >> 1; jj > 0; jj >>= 1) {
      if (tid < 128) {
        int p = tid ^ jj;
        if (p > tid) {
          int a = sidx[tid], b = sidx[p];
          bool up = ((tid & kk) == 0);
          if (up ? (a > b) : (a < b)) { sidx[tid] = b; sidx[p] = a; }
        }
      }
      __syncthreads();
    }
  if (tid < MM) {
    int mi = sidx[tid];
    minds[img*MM + tid] = mi;
    out[OUT_MI + img*MM + tid] = (float)mi;   // whole out buffer is float32
    vm[img*MM + tid] = fmax(vd[img*GG + mi], 1e-6) + 1e-10;
  }
}

// ============ K4: assemble A — SYMMETRIC tiles, gather fused (on-the-fly rows) ============
__global__ __launch_bounds__(256) void k_A(const float* __restrict__ pts,
                                           const int* __restrict__ minds,
                                           float* __restrict__ out, double* __restrict__ ad) {
  __shared__ float sxi[16][130], syi[16][130], sti[16][130];
  __shared__ float sxj[16][130], syj[16][130], stj[16][130];
  __shared__ float px[NN], py[NN];
  __shared__ float cxi[16], cyi[16], cxj[16], cyj[16];
  int bid = blockIdx.x;                 // img*28 + tri-tile
  int img = bid / 28;
  int tile = bid - img*28;
  int it = 0, trem = tile;
  while (trem >= 7 - it) { trem -= 7 - it; ++it; }
  int jt = it + trem;
  int i0 = it*16, j0 = jt*16;
  int tj = threadIdx.x & 15, ti = threadIdx.x >> 4;
  int i = i0 + ti, j = j0 + tj;
  const float CM = (float)(1.0/(2.0*M_PI*128.0));
  const float C1 = (float)(1.0/(2.0*M_PI*128.0));   // g1 scale (2*pi*2*sigma2)
  const float C2 = (float)(1.0/(2.0*M_PI*96.0));    // h scale (2*pi*s2)
  for (int s = threadIdx.x; s < NN; s += 256) {
    px[s] = pts[(img*NN + s)*2 + 0];
    py[s] = pts[(img*NN + s)*2 + 1];
  }
  if (threadIdx.x < 16) {
    int gi = i0 + (int)threadIdx.x; if (gi > 99) gi = 99;
    int mi = minds[img*MM + gi];
    cxi[threadIdx.x] = 8.0f*(mi & 63) + 4.0f;
    cyi[threadIdx.x] = 8.0f*(mi >> 6) + 4.0f;
  } else if (threadIdx.x < 32) {
    int r = (int)threadIdx.x - 16;
    int gj = j0 + r; if (gj > 99) gj = 99;
    int mj = minds[img*MM + gj];
    cxj[r] = 8.0f*(mj & 63) + 4.0f;
    cyj[r] = 8.0f*(mj >> 6) + 4.0f;
  }
  float aV = 0.0f, aM = 0.0f;
  for (int nc = 0; nc < NN; nc += 128) {
    __syncthreads();
    for (int s = threadIdx.x; s < 16*128; s += 256) {
      int row = s >> 7, n = s & 127;
      float x = px[nc + n], y = py[nc + n];
      float fxi = x - cxi[row], fyi = y - cyi[row];
      sxi[row][n] = fxi; syi[row][n] = fyi;
      sti[row][n] = __expf((fxi*fxi + fyi*fyi)*(-0.5f/128.0f))*CM;
      float fxj = x - cxj[row], fyj = y - cyj[row];
      sxj[row][n] = fxj; syj[row][n] = fyj;
      stj[row][n] = __expf((fxj*fxj + fyj*fyj)*(-0.5f/128.0f))*CM;
    }
    __syncthreads();
    #pragma unroll 4
    for (int n = 0; n < 128; ++n) {
      float xi = sxi[ti][n], yi = syi[ti][n], tii = sti[ti][n];
      float xj = sxj[tj][n], yj = syj[tj][n], tjj = stj[tj][n];
      float ddx = xj - xi, ddy = yj - yi;
      float df = ddx*ddx + ddy*ddy;
      float sx = 0.5f*(xi + xj), sy = 0.5f*(yi + yj);
      float af = sx*sx + sy*sy;
      float g1 = __expf(df*(-0.5f/128.0f))*C1;
      float h  = __expf(af*(-0.5f/96.0f))*C2;
      aV += g1 + g1*h;
      aM += tii*tjj;
    }
  }
  if (i < 100 && j < 100) {
    double val = (i == j) ? 1e-10 : ((double)aV - (double)aM);
    out[OUT_A + (img*MM + i)*MM + j] = (float)val;
    ad[(img*MM + i)*MM + j] = val;
    if (it != jt) {                     // mirror (diag tiles cover both in-tile)
      out[OUT_A + (img*MM + j)*MM + i] = (float)val;
      ad[(img*MM + j)*MM + i] = val;
    }
  }
}

// ============ K5a: m output — standalone, ZERO LDS, full occupancy ============
// SPLIT from the old fused k_inv_m: the 107.8 KB dynamic-LDS launch parameter
// was allocated for ALL 16392 blocks (LDS is per-dispatch), capping the
// streaming-write m-part at 1 block/CU -> 739 GB/s (9% of HBM peak).
// Standalone with 0 LDS it runs at full occupancy; pure write-BW-bound.
__global__ __launch_bounds__(256) void k_m(const float* __restrict__ pts,
                                           float* __restrict__ out) {
  int t = (int)blockIdx.x*256 + threadIdx.x;
  int e = t << 2;
  int img = e >> 21;
  int rem = e & ((1 << 21) - 1);
  int n = rem >> 12;
  int g = rem & 4095;
  int iy = g >> 6, ix = g & 63;         // e%4==0 -> ix%4==0
  const float CM = (float)(1.0/(2.0*M_PI*128.0));
  float x = pts[(img*NN + n)*2 + 0];
  float y = pts[(img*NN + n)*2 + 1];
  float dy = y - (8.0f*iy + 4.0f);
  float ey = __expf(dy*dy*(-0.5f/128.0f));
  float4 r;
  {
    float dx0 = x - (8.0f*ix + 4.0f);
    float dx1 = x - (8.0f*(ix+1) + 4.0f);
    float dx2 = x - (8.0f*(ix+2) + 4.0f);
    float dx3 = x - (8.0f*(ix+3) + 4.0f);
    r.x = ey*__expf(dx0*dx0*(-0.5f/128.0f))*CM;
    r.y = ey*__expf(dx1*dx1*(-0.5f/128.0f))*CM;
    r.z = ey*__expf(dx2*dx2*(-0.5f/128.0f))*CM;
    r.w = ey*__expf(dx3*dx3*(-0.5f/128.0f))*CM;
  }
  *reinterpret_cast<float4*>(&out[OUT_M + e]) = r;
}

// ============ K5b: no-pivot blocked fp64 GJ (SPD) -> Bm ============
__global__ __launch_bounds__(256)
void k_inv(const double* __restrict__ ad,
           const double* __restrict__ vm,
           float* __restrict__ out) {
  // dynamic LDS: S[128][17] | Mst[100][113]
  extern __shared__ double dyn[];
  double* S   = dyn;                    // 128*17 = 2176 doubles
  double* Mst = dyn + 2176;             // 100*113 = 11300 doubles
  __shared__ double svm[112];
  int img = blockIdx.x;
  int tx = threadIdx.x & 15, ty = threadIdx.x >> 4;   // ty in [0,16)
  double C[7][7];
  if (threadIdx.x < 100) svm[threadIdx.x] = vm[img*MM + threadIdx.x];
  // init C = A + diag(vM); rows/cols >= 100 -> 0
  #pragma unroll
  for (int a = 0; a < 7; ++a) {
    int r = ty + 16*a;
    #pragma unroll
    for (int b = 0; b < 7; ++b) {
      int j = tx + 16*b;
      double v2 = (r < 100 && j < 100) ? ad[(img*MM + r)*MM + j] : 0.0;
      if (r == j && r < 100) v2 += vm[img*MM + r];
      C[a][b] = v2;
    }
  }
  for (int p = 0; p < 7; ++p) {
    int k0 = p*16;
    int nbp = (p == 6) ? 4 : 16;
    // ---- P1: stage strip S + full C -> Mst
    #pragma unroll
    for (int a = 0; a < 7; ++a) {
      int r = ty + 16*a;
      double val = 0.0;
      #pragma unroll
      for (int b = 0; b < 7; ++b) if (b == p) val = C[a][b];
      S[r*17 + tx] = (r < 100 && tx < nbp) ? val : 0.0;
      if (r < 100) {
        #pragma unroll
        for (int b = 0; b < 7; ++b) Mst[r*113 + tx + 16*b] = C[a][b];
      }
    }
    __syncthreads();                                   // B1
    // ---- P2: wave 0 register-resident strip factorization (no pivoting)
    if (threadIdx.x < 64) {
      int lane = threadIdx.x;
      double P0[16], P1[16];
      #pragma unroll
      for (int c = 0; c < 16; ++c) {
        P0[c] = S[lane*17 + c];
        P1[c] = (lane + 64 < 112) ? S[(lane + 64)*17 + c] : 0.0;
      }
      #pragma unroll
      for (int kk = 0; kk < 16; ++kk) {
        if (kk < nbp) {
          int kg = k0 + kk;
          int r1 = lane + 64;
          bool khigh = kg >= 64; int kl = kg & 63;
          double pivinv = 1.0 / dbl_readlane(khigh ? P1[kk] : P0[kk], kl);
          double pr[16];
          #pragma unroll
          for (int c = 0; c < 16; ++c) {
            double pv = dbl_readlane(khigh ? P1[c] : P0[c], kl);
            pr[c] = (c == kk) ? pivinv : pv*pivinv;
          }
          {
            double f = P0[kk];
            if (lane == kg) {
              #pragma unroll
              for (int c = 0; c < 16; ++c) P0[c] = pr[c];
            } else {
              #pragma unroll
              for (int c = 0; c < 16; ++c) P0[c] = ((c == kk) ? 0.0 : P0[c]) - f*pr[c];
            }
          }
          {
            double f = P1[kk];
            if (r1 == kg) {
              #pragma unroll
              for (int c = 0; c < 16; ++c) P1[c] = pr[c];
            } else {
              #pragma unroll
              for (int c = 0; c < 16; ++c) P1[c] = ((c == kk) ? 0.0 : P1[c]) - f*pr[c];
            }
          }
        }
      }
      #pragma unroll
      for (int c = 0; c < 16; ++c) {
        S[lane*17 + c] = P0[c];
        if (lane + 64 < 112) S[(lane + 64)*17 + c] = P1[c];
      }
    }
    __syncthreads();                                   // B2
    // ---- P3: reload C (panel rows/col zeroed), trailing rank-16 update,
    //          panel-col writeback
    #pragma unroll
    for (int a = 0; a < 7; ++a) {
      int r = ty + 16*a;
      bool prow_ = (r >= k0) && (r < k0 + 16);
      #pragma unroll
      for (int b = 0; b < 7; ++b) {
        double v;
        if (r >= 100 || b == p || prow_) v = 0.0;
        else v = Mst[r*113 + tx + 16*b];
        C[a][b] = v;
      }
    }
    #pragma unroll 4
    for (int t = 0; t < 16; ++t) {
      bool tok = (t < nbp);
      double bt[7], sa[7];
      #pragma unroll
      for (int b = 0; b < 7; ++b) bt[b] = tok ? Mst[(k0 + t)*113 + tx + 16*b] : 0.0;
      #pragma unroll
      for (int a = 0; a < 7; ++a) sa[a] = S[(ty + 16*a)*17 + t];
      #pragma unroll
      for (int a = 0; a < 7; ++a)
        #pragma unroll
        for (int b = 0; b < 7; ++b) C[a][b] += sa[a]*bt[b];
    }
    #pragma unroll
    for (int a = 0; a < 7; ++a) {
      int r = ty + 16*a;
      double sval = S[r*17 + tx];
      #pragma unroll
      for (int b = 0; b < 7; ++b) if (b == p) C[a][b] = sval;
    }
    __syncthreads();                                   // B3 (WAR on S/Mst)
  }
  // Bm = Dv^{-1} - X
  #pragma unroll
  for (int a = 0; a < 7; ++a) {
    int r = ty + 16*a; if (r >= 100) continue;
    double dinv = 1.0 / svm[r];
    #pragma unroll
    for (int b = 0; b < 7; ++b) {
      int c = tx + 16*b; if (c >= 100) continue;
      double val = ((c == r) ? dinv : 0.0) - C[a][b];
      out[OUT_B + (img*MM + r)*MM + c] = (float)val;
    }
  }
}

extern "C" void kernel_launch(void* const* d_in, const int* in_sizes, int n_in,
                              void* d_out, int out_size, void* d_ws, size_t ws_size,
                              hipStream_t stream) {
  const float* pts = (const float*)d_in[0];
  float* out = (float*)d_out;
  char* ws = (char*)d_ws;
  double* vd  = (double*)(ws + OFF_VD);
  double* vmd = (double*)(ws + OFF_VM);
  double* ad  = (double*)(ws + OFF_AD);
  int* minds = (int*)(ws + OFF_MIND);

  // k_m only depends on pts — launch first (independent of the rest).
  hipLaunchKernelGGL(k_m, dim3((BB*NN*GG)/(256*4)), dim3(256), 0, stream, pts, out);
  hipLaunchKernelGGL(k_vpart, dim3(BB*16), dim3(256), 0, stream, pts, vd);
  hipLaunchKernelGGL(k_select, dim3(BB), dim3(256), 0, stream, vd, out, minds, vmd);
  hipLaunchKernelGGL(k_A, dim3(BB*28), dim3(256), 0, stream, pts, minds, out, ad);
  size_t invLds = (size_t)(2176 + 11300) * sizeof(double);  // 107,808 B
  hipLaunchKernelGGL(k_inv, dim3(BB), dim3(256), invLds, stream, ad, vmd, out);
}

// Round 2
// 293.468 us; speedup vs baseline: 1.0370x; 1.0370x over previous
//
#include <hip/hip_runtime.h>
#include <math.h>

#ifndef M_PI
#define M_PI 3.14159265358979323846
#endif

#define BB 8
#define NN 512
#define KK 64
#define GG 4096
#define MM 100

// ---------------- workspace layout (byte offsets) ----------------
#define SZ_VD    (BB*GG*8u)
#define OFF_VD   0u
#define SZ_VM    (BB*MM*8u)
#define OFF_VM   (OFF_VD + SZ_VD)
#define SZ_AD    (BB*MM*MM*8u)
#define OFF_AD   (OFF_VM + SZ_VM)
#define OFF_MIND (OFF_AD + SZ_AD)

// ---------------- output layout (float element offsets) ----------------
#define OUT_M  0
#define OUT_V  (BB*NN*GG)               // 16,777,216
#define OUT_A  (OUT_V + BB*GG)          // 16,809,984
#define OUT_B  (OUT_A + BB*MM*MM)      // 16,889,984
#define OUT_MI (OUT_B + BB*MM*MM)      // 16,969,984

// ---------------- fast wave64 argmax (value, first-index) ----------------
#if __has_builtin(__builtin_amdgcn_update_dpp)
#define HAVE_DPP 1
#endif

__device__ __forceinline__ void wave_argmax(double v, int idx, double& out_v, int& out_i) {
#ifdef HAVE_DPP
#define DPPSTEP(CTRL) { \
    unsigned long long b = (unsigned long long)__double_as_longlong(v); \
    int slo = (int)(unsigned)(b & 0xffffffffull); \
    int shi = (int)(unsigned)(b >> 32); \
    unsigned lo = (unsigned)__builtin_amdgcn_update_dpp(slo, slo, CTRL, 0xf, 0xf, false); \
    unsigned hi = (unsigned)__builtin_amdgcn_update_dpp(shi, shi, CTRL, 0xf, 0xf, false); \
    double ov = __longlong_as_double((long long)(((unsigned long long)hi << 32) | lo)); \
    int oi = __builtin_amdgcn_update_dpp(idx, idx, CTRL, 0xf, 0xf, false); \
    if (ov > v || (ov == v && oi < idx)) { v = ov; idx = oi; } }
  DPPSTEP(0x111)  // row_shr:1
  DPPSTEP(0x112)  // row_shr:2
  DPPSTEP(0x114)  // row_shr:4
  DPPSTEP(0x118)  // row_shr:8
  DPPSTEP(0x142)  // row_bcast:15
  DPPSTEP(0x143)  // row_bcast:31
#undef DPPSTEP
  {
    unsigned long long b = (unsigned long long)__double_as_longlong(v);
    unsigned lo = (unsigned)__builtin_amdgcn_readlane((int)(unsigned)(b & 0xffffffffull), 63);
    unsigned hi = (unsigned)__builtin_amdgcn_readlane((int)(unsigned)(b >> 32), 63);
    out_v = __longlong_as_double((long long)(((unsigned long long)hi << 32) | lo));
    out_i = __builtin_amdgcn_readlane(idx, 63);
  }
#else
  for (int off = 32; off; off >>= 1) {
    double ov = __shfl_down(v, off);
    int oi = __shfl_down(idx, off);
    if (ov > v || (ov == v && oi < idx)) { v = ov; idx = oi; }
  }
  out_v = __shfl(v, 0); out_i = __shfl(idx, 0);
#endif
}

__device__ __forceinline__ double dbl_readlane(double v, int l) {
  long long b = __double_as_longlong(v);
  int lo = __builtin_amdgcn_readlane((int)(unsigned)((unsigned long long)b & 0xffffffffull), l);
  int hi = __builtin_amdgcn_readlane((int)(unsigned)((unsigned long long)b >> 32), l);
  return __longlong_as_double((long long)(((unsigned long long)(unsigned)hi << 32) | (unsigned)lo));
}

// ============ K2: v — two 64x64 matmuls, FULL-K, exp tables computed ON THE FLY ============
__global__ __launch_bounds__(256) void k_vpart(const float* __restrict__ pts,
                                               double* __restrict__ vd) {
  __shared__ double sEy2[16][66], sEx2[16][66], sEy3[16][66], sEx3[16][66];
  __shared__ float px[NN], py[NN];
  int bid = blockIdx.x;                 // img*16 + tile
  int tile = bid & 15;
  int img = bid >> 4;
  int iy0 = (tile >> 2) << 4;
  int ix0 = (tile & 3) << 4;
  int tx = threadIdx.x & 15, ty = threadIdx.x >> 4;
  for (int s = threadIdx.x; s < NN; s += 256) {
    px[s] = pts[(img*NN + s)*2 + 0];
    py[s] = pts[(img*NN + s)*2 + 1];
  }
  double aV = 0.0, aM = 0.0;
  for (int kc = 0; kc < 8; ++kc) {
    int nb = kc << 6;
    __syncthreads();                    // WAR on LDS (and px/py ready on kc=0)
    for (int s = threadIdx.x; s < 16*64; s += 256) {
      int row = s >> 6, n = s & 63;
      int nn = nb + n;
      double y = (double)py[nn];
      double cy = 8.0*(iy0 + row) + 4.0;
      double dy = y - cy, dy2 = dy*dy;
      sEy2[row][n] = exp(dy2*(-0.5/96.0));
      sEy3[row][n] = exp(dy2*(-1.0/128.0));
      double x = (double)px[nn];
      double cx = 8.0*(ix0 + row) + 4.0;
      double dx = x - cx, dx2 = dx*dx;
      sEx2[row][n] = exp(dx2*(-0.5/96.0));
      sEx3[row][n] = exp(dx2*(-1.0/128.0));
    }
    __syncthreads();
    #pragma unroll 8
    for (int n = 0; n < 64; ++n) {
      aV += sEy2[ty][n]*sEx2[tx][n];
      aM += sEy3[ty][n]*sEx3[tx][n];
    }
  }
  const double CTV = 1.0/((2.0*M_PI*96.0)*(2.0*M_PI*128.0));
  const double CM2 = 1.0/((2.0*M_PI*128.0)*(2.0*M_PI*128.0));
  vd[img*GG + (iy0 + ty)*KK + ix0 + tx] = CTV*aV - CM2*aM;
}

// ============ K3: top-100 select + v output — SINGLE-WAVE, BARRIER-FREE loop ============
__global__ __launch_bounds__(256) void k_select(const double* __restrict__ vd,
                                                float* __restrict__ out,
                                                int* __restrict__ minds,
                                                double* __restrict__ vm) {
  __shared__ double sv[GG + 64];        // padded: g -> g + (g>>6)  (rescan conflict-free)
  __shared__ int selbuf[MM];
  __shared__ int sidx[128];
  int img = blockIdx.x;
  int tid = threadIdx.x;
  for (int s = tid; s < GG; s += 256) {
    double v = vd[img*GG + s];
    sv[s + (s >> 6)] = v;
    out[OUT_V + img*GG + s] = (float)fmax(v, 1e-6);
  }
  __syncthreads();
  if (tid < 64) {
    int lane = tid;
    volatile double* svv = sv;
    double bv = -1e300; int gi = lane;
    #pragma unroll 8
    for (int c = 0; c < 64; ++c) {
      int g = c*64 + lane;
      double v = sv[g + c];             // g>>6 == c
      if (v > bv) { bv = v; gi = g; }
    }
    for (int r = 0; r < MM; ++r) {
      double gv; int gidx;
      wave_argmax(bv, gi, gv, gidx);
      if (lane == 0) selbuf[r] = gidx;
      int owner = gidx & 63;
      if (lane == owner) svv[gidx + (gidx >> 6)] = -1e300;
      int g2 = lane*64 + owner;         // c = lane
      double nv = svv[g2 + lane];       // g2>>6 == lane
      double nbv; int ngi;
      wave_argmax(nv, g2, nbv, ngi);
      if (lane == owner) { bv = nbv; gi = ngi; }
    }
  }
  __syncthreads();
  // sort the 100 selected indices ascending (bitonic over 128)
  if (tid < 128) sidx[tid] = (tid < MM) ? selbuf[tid] : 0x7fffffff;
  __syncthreads();
  for (int kk = 2; kk <= 128; kk <<= 1)
    for (int jj = kk >> 1; jj > 0; jj >>= 1) {
      if (tid < 128) {
        int p = tid ^ jj;
        if (p > tid) {
          int a = sidx[tid], b = sidx[p];
          bool up = ((tid & kk) == 0);
          if (up ? (a > b) : (a < b)) { sidx[tid] = b; sidx[p] = a; }
        }
      }
      __syncthreads();
    }
  if (tid < MM) {
    int mi = sidx[tid];
    minds[img*MM + tid] = mi;
    out[OUT_MI + img*MM + tid] = (float)mi;   // whole out buffer is float32
    vm[img*MM + tid] = fmax(vd[img*GG + mi], 1e-6) + 1e-10;
  }
}

// ============ K4: assemble A — SYMMETRIC tiles, gather fused (on-the-fly rows) ============
__global__ __launch_bounds__(256) void k_A(const float* __restrict__ pts,
                                           const int* __restrict__ minds,
                                           float* __restrict__ out, double* __restrict__ ad) {
  __shared__ float sxi[16][130], syi[16][130], sti[16][130];
  __shared__ float sxj[16][130], syj[16][130], stj[16][130];
  __shared__ float px[NN], py[NN];
  __shared__ float cxi[16], cyi[16], cxj[16], cyj[16];
  int bid = blockIdx.x;                 // img*28 + tri-tile
  int img = bid / 28;
  int tile = bid - img*28;
  int it = 0, trem = tile;
  while (trem >= 7 - it) { trem -= 7 - it; ++it; }
  int jt = it + trem;
  int i0 = it*16, j0 = jt*16;
  int tj = threadIdx.x & 15, ti = threadIdx.x >> 4;
  int i = i0 + ti, j = j0 + tj;
  const float CM = (float)(1.0/(2.0*M_PI*128.0));
  const float C1 = (float)(1.0/(2.0*M_PI*128.0));   // g1 scale (2*pi*2*sigma2)
  const float C2 = (float)(1.0/(2.0*M_PI*96.0));    // h scale (2*pi*s2)
  for (int s = threadIdx.x; s < NN; s += 256) {
    px[s] = pts[(img*NN + s)*2 + 0];
    py[s] = pts[(img*NN + s)*2 + 1];
  }
  if (threadIdx.x < 16) {
    int gi = i0 + (int)threadIdx.x; if (gi > 99) gi = 99;
    int mi = minds[img*MM + gi];
    cxi[threadIdx.x] = 8.0f*(mi & 63) + 4.0f;
    cyi[threadIdx.x] = 8.0f*(mi >> 6) + 4.0f;
  } else if (threadIdx.x < 32) {
    int r = (int)threadIdx.x - 16;
    int gj = j0 + r; if (gj > 99) gj = 99;
    int mj = minds[img*MM + gj];
    cxj[r] = 8.0f*(mj & 63) + 4.0f;
    cyj[r] = 8.0f*(mj >> 6) + 4.0f;
  }
  float aV = 0.0f, aM = 0.0f;
  for (int nc = 0; nc < NN; nc += 128) {
    __syncthreads();
    for (int s = threadIdx.x; s < 16*128; s += 256) {
      int row = s >> 7, n = s & 127;
      float x = px[nc + n], y = py[nc + n];
      float fxi = x - cxi[row], fyi = y - cyi[row];
      sxi[row][n] = fxi; syi[row][n] = fyi;
      sti[row][n] = __expf((fxi*fxi + fyi*fyi)*(-0.5f/128.0f))*CM;
      float fxj = x - cxj[row], fyj = y - cyj[row];
      sxj[row][n] = fxj; syj[row][n] = fyj;
      stj[row][n] = __expf((fxj*fxj + fyj*fyj)*(-0.5f/128.0f))*CM;
    }
    __syncthreads();
    #pragma unroll 4
    for (int n = 0; n < 128; ++n) {
      float xi = sxi[ti][n], yi = syi[ti][n], tii = sti[ti][n];
      float xj = sxj[tj][n], yj = syj[tj][n], tjj = stj[tj][n];
      float ddx = xj - xi, ddy = yj - yi;
      float df = ddx*ddx + ddy*ddy;
      float sx = 0.5f*(xi + xj), sy = 0.5f*(yi + yj);
      float af = sx*sx + sy*sy;
      float g1 = __expf(df*(-0.5f/128.0f))*C1;
      float h  = __expf(af*(-0.5f/96.0f))*C2;
      aV += g1 + g1*h;
      aM += tii*tjj;
    }
  }
  if (i < 100 && j < 100) {
    double val = (i == j) ? 1e-10 : ((double)aV - (double)aM);
    out[OUT_A + (img*MM + i)*MM + j] = (float)val;
    ad[(img*MM + i)*MM + j] = val;
    if (it != jt) {                     // mirror (diag tiles cover both in-tile)
      out[OUT_A + (img*MM + j)*MM + i] = (float)val;
      ad[(img*MM + j)*MM + i] = val;
    }
  }
}

// ============ K5: fused GJ inversion (blocks 0..7) + m output (blocks 8..) ============
// LDS cut from 107.8 KB -> exactly 32 KB: the Mst[100][113] full-C round-trip
// was redundant (C lives in registers, untouched P1->P3; P3's "reload with
// masking" is register masking). Only the 16 PANEL ROWS need cross-thread
// staging: Pr[16][113] (14.4 KB). With 32 KB/block the fused m-part runs at
// ~5 blocks/CU (vs 1 before) AND the inversion overlaps the m writes, so the
// machine stays busy/clocked during the inversion instead of 8/256 CUs active.
__global__ __launch_bounds__(256)
void k_inv_m(const double* __restrict__ ad,
             const double* __restrict__ vm,
             const float* __restrict__ pts,
             float* __restrict__ out) {
  __shared__ double S[128*17];          // 17,408 B
  __shared__ double Pr[16*113];         // 14,464 B
  __shared__ double svm[112];           //    896 B  -> total 32,768 B
  if (blockIdx.x >= BB) {
    // ---- m part: 4 elems per thread; pure streaming float4 writes
    int t = (int)(blockIdx.x - BB)*256 + threadIdx.x;
    int e = t << 2;
    int img = e >> 21;
    int rem = e & ((1 << 21) - 1);
    int n = rem >> 12;
    int g = rem & 4095;
    int iy = g >> 6, ix = g & 63;       // e%4==0 -> ix%4==0
    const float CM = (float)(1.0/(2.0*M_PI*128.0));
    float x = pts[(img*NN + n)*2 + 0];
    float y = pts[(img*NN + n)*2 + 1];
    float dy = y - (8.0f*iy + 4.0f);
    float ey = __expf(dy*dy*(-0.5f/128.0f));
    float4 r;
    {
      float dx0 = x - (8.0f*ix + 4.0f);
      float dx1 = x - (8.0f*(ix+1) + 4.0f);
      float dx2 = x - (8.0f*(ix+2) + 4.0f);
      float dx3 = x - (8.0f*(ix+3) + 4.0f);
      r.x = ey*__expf(dx0*dx0*(-0.5f/128.0f))*CM;
      r.y = ey*__expf(dx1*dx1*(-0.5f/128.0f))*CM;
      r.z = ey*__expf(dx2*dx2*(-0.5f/128.0f))*CM;
      r.w = ey*__expf(dx3*dx3*(-0.5f/128.0f))*CM;
    }
    *reinterpret_cast<float4*>(&out[OUT_M + e]) = r;
    return;
  }
  // ---- inversion part: no-pivot blocked fp64 GJ (SPD), Bm = Dv^{-1} - (A+Dv)^{-1}
  int img = blockIdx.x;
  int tx = threadIdx.x & 15, ty = threadIdx.x >> 4;   // ty in [0,16)
  double C[7][7];
  if (threadIdx.x < 100) svm[threadIdx.x] = vm[img*MM + threadIdx.x];
  // init C = A + diag(vM); rows/cols >= 100 -> 0
  #pragma unroll
  for (int a = 0; a < 7; ++a) {
    int r = ty + 16*a;
    #pragma unroll
    for (int b = 0; b < 7; ++b) {
      int j = tx + 16*b;
      double v2 = (r < 100 && j < 100) ? ad[(img*MM + r)*MM + j] : 0.0;
      if (r == j && r < 100) v2 += vm[img*MM + r];
      C[a][b] = v2;
    }
  }
  for (int p = 0; p < 7; ++p) {
    int k0 = p*16;
    int nbp = (p == 6) ? 4 : 16;
    // ---- P1: stage panel-col strip S + panel rows Pr (phase-start values)
    #pragma unroll
    for (int a = 0; a < 7; ++a) {
      int r = ty + 16*a;
      double val = 0.0;
      #pragma unroll
      for (int b = 0; b < 7; ++b) if (b == p) val = C[a][b];
      S[r*17 + tx] = (r < 100 && tx < nbp) ? val : 0.0;
    }
    {
      // panel rows k0..k0+15 are owned by row-block a==p: thread (ty,tx) holds
      // C[p][b] = element (k0+ty, tx+16b). Static-index extract via predication.
      double pv[7];
      #pragma unroll
      for (int b = 0; b < 7; ++b) pv[b] = 0.0;
      #pragma unroll
      for (int a = 0; a < 7; ++a) {
        #pragma unroll
        for (int b = 0; b < 7; ++b) if (a == p) pv[b] = C[a][b];
      }
      #pragma unroll
      for (int b = 0; b < 7; ++b) Pr[ty*113 + tx + 16*b] = pv[b];
    }
    __syncthreads();                                   // B1
    // ---- P2: wave 0 register-resident strip factorization (no pivoting)
    if (threadIdx.x < 64) {
      int lane = threadIdx.x;
      double P0[16], P1[16];
      #pragma unroll
      for (int c = 0; c < 16; ++c) {
        P0[c] = S[lane*17 + c];
        P1[c] = (lane + 64 < 112) ? S[(lane + 64)*17 + c] : 0.0;
      }
      #pragma unroll
      for (int kk = 0; kk < 16; ++kk) {
        if (kk < nbp) {
          int kg = k0 + kk;
          int r1 = lane + 64;
          bool khigh = kg >= 64; int kl = kg & 63;
          double pivinv = 1.0 / dbl_readlane(khigh ? P1[kk] : P0[kk], kl);
          double pr[16];
          #pragma unroll
          for (int c = 0; c < 16; ++c) {
            double pv = dbl_readlane(khigh ? P1[c] : P0[c], kl);
            pr[c] = (c == kk) ? pivinv : pv*pivinv;
          }
          {
            double f = P0[kk];
            if (lane == kg) {
              #pragma unroll
              for (int c = 0; c < 16; ++c) P0[c] = pr[c];
            } else {
              #pragma unroll
              for (int c = 0; c < 16; ++c) P0[c] = ((c == kk) ? 0.0 : P0[c]) - f*pr[c];
            }
          }
          {
            double f = P1[kk];
            if (r1 == kg) {
              #pragma unroll
              for (int c = 0; c < 16; ++c) P1[c] = pr[c];
            } else {
              #pragma unroll
              for (int c = 0; c < 16; ++c) P1[c] = ((c == kk) ? 0.0 : P1[c]) - f*pr[c];
            }
          }
        }
      }
      #pragma unroll
      for (int c = 0; c < 16; ++c) {
        S[lane*17 + c] = P0[c];
        if (lane + 64 < 112) S[(lane + 64)*17 + c] = P1[c];
      }
    }
    __syncthreads();                                   // B2
    // ---- P3: mask C in REGISTERS (panel rows/col + r>=100 zeroed),
    //          trailing rank-16 update from Pr, panel-col writeback from S
    #pragma unroll
    for (int a = 0; a < 7; ++a) {
      int r = ty + 16*a;
      bool prow_ = (r >= k0) && (r < k0 + 16);
      #pragma unroll
      for (int b = 0; b < 7; ++b) {
        if (r >= 100 || b == p || prow_) C[a][b] = 0.0;
      }
    }
    #pragma unroll 4
    for (int t = 0; t < 16; ++t) {
      bool tok = (t < nbp);
      double bt[7], sa[7];
      #pragma unroll
      for (int b = 0; b < 7; ++b) bt[b] = tok ? Pr[t*113 + tx + 16*b] : 0.0;
      #pragma unroll
      for (int a = 0; a < 7; ++a) sa[a] = S[(ty + 16*a)*17 + t];
      #pragma unroll
      for (int a = 0; a < 7; ++a)
        #pragma unroll
        for (int b = 0; b < 7; ++b) C[a][b] += sa[a]*bt[b];
    }
    #pragma unroll
    for (int a = 0; a < 7; ++a) {
      int r = ty + 16*a;
      double sval = S[r*17 + tx];
      #pragma unroll
      for (int b = 0; b < 7; ++b) if (b == p) C[a][b] = sval;
    }
    __syncthreads();                                   // B3 (WAR on S/Pr)
  }
  // Bm = Dv^{-1} - X
  #pragma unroll
  for (int a = 0; a < 7; ++a) {
    int r = ty + 16*a; if (r >= 100) continue;
    double dinv = 1.0 / svm[r];
    #pragma unroll
    for (int b = 0; b < 7; ++b) {
      int c = tx + 16*b; if (c >= 100) continue;
      double val = ((c == r) ? dinv : 0.0) - C[a][b];
      out[OUT_B + (img*MM + r)*MM + c] = (float)val;
    }
  }
}

extern "C" void kernel_launch(void* const* d_in, const int* in_sizes, int n_in,
                              void* d_out, int out_size, void* d_ws, size_t ws_size,
                              hipStream_t stream) {
  const float* pts = (const float*)d_in[0];
  float* out = (float*)d_out;
  char* ws = (char*)d_ws;
  double* vd  = (double*)(ws + OFF_VD);
  double* vmd = (double*)(ws + OFF_VM);
  double* ad  = (double*)(ws + OFF_AD);
  int* minds = (int*)(ws + OFF_MIND);

  hipLaunchKernelGGL(k_vpart, dim3(BB*16), dim3(256), 0, stream, pts, vd);
  hipLaunchKernelGGL(k_select, dim3(BB), dim3(256), 0, stream, vd, out, minds, vmd);
  hipLaunchKernelGGL(k_A, dim3(BB*28), dim3(256), 0, stream, pts, minds, out, ad);
  hipLaunchKernelGGL(k_inv_m, dim3(BB + (BB*NN*GG)/(256*4)), dim3(256), 0, stream,
                     ad, vmd, pts, out);
}

// Round 3
// 235.561 us; speedup vs baseline: 1.2919x; 1.2458x over previous
//
#include <hip/hip_runtime.h>
#include <math.h>

#ifndef M_PI
#define M_PI 3.14159265358979323846
#endif

#define BB 8
#define NN 512
#define KK 64
#define GG 4096
#define MM 100

// ---------------- workspace layout (byte offsets) ----------------
#define SZ_VD    (BB*GG*8u)
#define OFF_VD   0u
#define SZ_VM    (BB*MM*8u)
#define OFF_VM   (OFF_VD + SZ_VD)
#define SZ_AD    (BB*MM*MM*8u)
#define OFF_AD   (OFF_VM + SZ_VM)
#define OFF_MIND (OFF_AD + SZ_AD)

// ---------------- output layout (float element offsets) ----------------
#define OUT_M  0
#define OUT_V  (BB*NN*GG)               // 16,777,216
#define OUT_A  (OUT_V + BB*GG)          // 16,809,984
#define OUT_B  (OUT_A + BB*MM*MM)      // 16,889,984
#define OUT_MI (OUT_B + BB*MM*MM)      // 16,969,984

__device__ __forceinline__ double dbl_readlane(double v, int l) {
  long long b = __double_as_longlong(v);
  int lo = __builtin_amdgcn_readlane((int)(unsigned)((unsigned long long)b & 0xffffffffull), l);
  int hi = __builtin_amdgcn_readlane((int)(unsigned)((unsigned long long)b >> 32), l);
  return __longlong_as_double((long long)(((unsigned long long)(unsigned)hi << 32) | (unsigned)lo));
}

// ============ K2: v — two 64x64 matmuls, FULL-K, exp tables computed ON THE FLY ============
__global__ __launch_bounds__(256) void k_vpart(const float* __restrict__ pts,
                                               double* __restrict__ vd) {
  __shared__ double sEy2[16][66], sEx2[16][66], sEy3[16][66], sEx3[16][66];
  __shared__ float px[NN], py[NN];
  int bid = blockIdx.x;                 // img*16 + tile
  int tile = bid & 15;
  int img = bid >> 4;
  int iy0 = (tile >> 2) << 4;
  int ix0 = (tile & 3) << 4;
  int tx = threadIdx.x & 15, ty = threadIdx.x >> 4;
  for (int s = threadIdx.x; s < NN; s += 256) {
    px[s] = pts[(img*NN + s)*2 + 0];
    py[s] = pts[(img*NN + s)*2 + 1];
  }
  double aV = 0.0, aM = 0.0;
  for (int kc = 0; kc < 8; ++kc) {
    int nb = kc << 6;
    __syncthreads();                    // WAR on LDS (and px/py ready on kc=0)
    for (int s = threadIdx.x; s < 16*64; s += 256) {
      int row = s >> 6, n = s & 63;
      int nn = nb + n;
      double y = (double)py[nn];
      double cy = 8.0*(iy0 + row) + 4.0;
      double dy = y - cy, dy2 = dy*dy;
      sEy2[row][n] = exp(dy2*(-0.5/96.0));
      sEy3[row][n] = exp(dy2*(-1.0/128.0));
      double x = (double)px[nn];
      double cx = 8.0*(ix0 + row) + 4.0;
      double dx = x - cx, dx2 = dx*dx;
      sEx2[row][n] = exp(dx2*(-0.5/96.0));
      sEx3[row][n] = exp(dx2*(-1.0/128.0));
    }
    __syncthreads();
    #pragma unroll 8
    for (int n = 0; n < 64; ++n) {
      aV += sEy2[ty][n]*sEx2[tx][n];
      aM += sEy3[ty][n]*sEx3[tx][n];
    }
  }
  const double CTV = 1.0/((2.0*M_PI*96.0)*(2.0*M_PI*128.0));
  const double CM2 = 1.0/((2.0*M_PI*128.0)*(2.0*M_PI*128.0));
  vd[img*GG + (iy0 + ty)*KK + ix0 + tx] = CTV*aV - CM2*aM;
}

// ---------------- bitonic sort of 128 ints ascending (shared array) ----------------
__device__ __forceinline__ void bitonic128(int* a, int tid) {
  for (int kk = 2; kk <= 128; kk <<= 1)
    for (int jj = kk >> 1; jj > 0; jj >>= 1) {
      if (tid < 128) {
        int p = tid ^ jj;
        if (p > tid) {
          int x = a[tid], y = a[p];
          bool up = ((tid & kk) == 0);
          if (up ? (x > y) : (x < y)) { a[tid] = y; a[p] = x; }
        }
      }
      __syncthreads();
    }
}

// ============ K3: top-100 select — DATA-PARALLEL RADIX SELECT ============
// Replaces the single-wave 100-round serial argmax (86 µs, VALUBusy 0.27% —
// pure DPP/readlane dependency-chain latency) with an MSB-first 8x8-bit radix
// select on sortable uint64 keys: 8 parallel passes over 16 keys/thread.
// Exact semantics of stable argsort(-v)[:100]: full 64-bit threshold T;
// #(k>T) taken unconditionally, remaining r taken from ==T by SMALLEST index.
// Per-wave split histograms (4 copies) bound same-address LDS atomic
// serialization on the exponent-clustered early passes.
__global__ __launch_bounds__(256) void k_select(const double* __restrict__ vd,
                                                float* __restrict__ out,
                                                int* __restrict__ minds,
                                                double* __restrict__ vm) {
  __shared__ unsigned long long ku[GG];        // 32 KB sortable keys
  __shared__ unsigned int hist4[4][256];       // per-wave histogram copies
  __shared__ unsigned int suf[257];            // suffix sums (+guard)
  __shared__ unsigned long long sPrefPlaced;   // chosen high bits, in place
  __shared__ unsigned long long sMaskHi;       // mask of decided bits
  __shared__ unsigned int sRem, sPickB, sPickRem, sCGt, sCEq;
  __shared__ int sel[128];
  __shared__ int tie[128];
  int img = blockIdx.x;
  int tid = threadIdx.x;
  int wv = tid >> 6;
  // load, emit v output, build monotonic keys (desc v == desc unsigned key)
  for (int t = 0; t < 16; ++t) {
    int g = t*256 + tid;                       // consecutive lanes -> consecutive addrs
    double v = vd[img*GG + g];
    out[OUT_V + img*GG + g] = (float)fmax(v, 1e-6);
    long long u = __double_as_longlong(v);
    unsigned long long k = (u < 0) ? ~(unsigned long long)u
                                   : ((unsigned long long)u | 0x8000000000000000ull);
    ku[g] = k;
  }
  if (tid == 0) {
    sRem = 100; sPrefPlaced = 0ull; sMaskHi = 0ull;
    sCGt = 0; sCEq = 0; suf[256] = 0;
  }
  // ---- 8 radix passes, MSB first ----
  for (int shift = 56; shift >= 0; shift -= 8) {
    for (int c = 0; c < 4; ++c) hist4[c][tid] = 0;
    __syncthreads();                            // ku ready / hist zeroed / state stable
    unsigned long long maskHi = sMaskHi, prefP = sPrefPlaced;
    for (int t = 0; t < 16; ++t) {
      int g = t*256 + tid;
      unsigned long long k = ku[g];
      if ((k & maskHi) == prefP) {
        unsigned d = (unsigned)((k >> shift) & 255ull);
        atomicAdd(&hist4[wv][d], 1u);
      }
    }
    __syncthreads();
    suf[tid] = hist4[0][tid] + hist4[1][tid] + hist4[2][tid] + hist4[3][tid];
    __syncthreads();
    for (int off = 1; off < 256; off <<= 1) {   // Hillis-Steele suffix sum
      unsigned add = (tid + off < 256) ? suf[tid + off] : 0u;
      __syncthreads();
      suf[tid] += add;
      __syncthreads();
    }
    unsigned rem = sRem;
    unsigned sgt = (tid < 255) ? suf[tid + 1] : 0u;
    if (suf[tid] >= rem && sgt < rem) { sPickB = (unsigned)tid; sPickRem = rem - sgt; }
    __syncthreads();
    if (tid == 0) {
      sPrefPlaced |= ((unsigned long long)sPickB) << shift;
      sMaskHi     |= (255ull << shift);
      sRem = sPickRem;
    }
    __syncthreads();
  }
  // ---- collect: all k > T, plus r smallest-index ties (k == T) ----
  unsigned long long T = sPrefPlaced;           // exact 100th-largest key
  for (int t = 0; t < 16; ++t) {
    int g = t*256 + tid;
    unsigned long long k = ku[g];
    if (k > T) {
      unsigned p = atomicAdd(&sCGt, 1u);        // p <= 98 always (count < 100)
      sel[p] = g;
    } else if (k == T) {
      unsigned p = atomicAdd(&sCEq, 1u);
      if (p < 128) tie[p] = g;                  // >128 exact-equal boundary values:
    }                                           // pathological, not hit by real data
  }
  __syncthreads();
  unsigned cgt = sCGt, ceq = sCEq, r = sRem;    // cgt + r == 100, 1 <= r <= ceq
  if (tid < 128 && tid >= (int)((ceq < 128u) ? ceq : 128u)) tie[tid] = 0x7fffffff;
  __syncthreads();
  bitonic128(tie, tid);                          // ties ascending by index
  if (tid < (int)r) sel[cgt + tid] = tie[tid];   // take r smallest-index ties
  if (tid >= MM && tid < 128) sel[tid] = 0x7fffffff;
  __syncthreads();
  bitonic128(sel, tid);                          // final Minds ascending
  if (tid < MM) {
    int mi = sel[tid];
    minds[img*MM + tid] = mi;
    out[OUT_MI + img*MM + tid] = (float)mi;      // whole out buffer is float32
    vm[img*MM + tid] = fmax(vd[img*GG + mi], 1e-6) + 1e-10;
  }
}

// ============ K4: assemble A — SYMMETRIC tiles, gather fused (on-the-fly rows) ============
__global__ __launch_bounds__(256) void k_A(const float* __restrict__ pts,
                                           const int* __restrict__ minds,
                                           float* __restrict__ out, double* __restrict__ ad) {
  __shared__ float sxi[16][130], syi[16][130], sti[16][130];
  __shared__ float sxj[16][130], syj[16][130], stj[16][130];
  __shared__ float px[NN], py[NN];
  __shared__ float cxi[16], cyi[16], cxj[16], cyj[16];
  int bid = blockIdx.x;                 // img*28 + tri-tile
  int img = bid / 28;
  int tile = bid - img*28;
  int it = 0, trem = tile;
  while (trem >= 7 - it) { trem -= 7 - it; ++it; }
  int jt = it + trem;
  int i0 = it*16, j0 = jt*16;
  int tj = threadIdx.x & 15, ti = threadIdx.x >> 4;
  int i = i0 + ti, j = j0 + tj;
  const float CM = (float)(1.0/(2.0*M_PI*128.0));
  const float C1 = (float)(1.0/(2.0*M_PI*128.0));   // g1 scale (2*pi*2*sigma2)
  const float C2 = (float)(1.0/(2.0*M_PI*96.0));    // h scale (2*pi*s2)
  for (int s = threadIdx.x; s < NN; s += 256) {
    px[s] = pts[(img*NN + s)*2 + 0];
    py[s] = pts[(img*NN + s)*2 + 1];
  }
  if (threadIdx.x < 16) {
    int gi = i0 + (int)threadIdx.x; if (gi > 99) gi = 99;
    int mi = minds[img*MM + gi];
    cxi[threadIdx.x] = 8.0f*(mi & 63) + 4.0f;
    cyi[threadIdx.x] = 8.0f*(mi >> 6) + 4.0f;
  } else if (threadIdx.x < 32) {
    int r = (int)threadIdx.x - 16;
    int gj = j0 + r; if (gj > 99) gj = 99;
    int mj = minds[img*MM + gj];
    cxj[r] = 8.0f*(mj & 63) + 4.0f;
    cyj[r] = 8.0f*(mj >> 6) + 4.0f;
  }
  float aV = 0.0f, aM = 0.0f;
  for (int nc = 0; nc < NN; nc += 128) {
    __syncthreads();
    for (int s = threadIdx.x; s < 16*128; s += 256) {
      int row = s >> 7, n = s & 127;
      float x = px[nc + n], y = py[nc + n];
      float fxi = x - cxi[row], fyi = y - cyi[row];
      sxi[row][n] = fxi; syi[row][n] = fyi;
      sti[row][n] = __expf((fxi*fxi + fyi*fyi)*(-0.5f/128.0f))*CM;
      float fxj = x - cxj[row], fyj = y - cyj[row];
      sxj[row][n] = fxj; syj[row][n] = fyj;
      stj[row][n] = __expf((fxj*fxj + fyj*fyj)*(-0.5f/128.0f))*CM;
    }
    __syncthreads();
    #pragma unroll 4
    for (int n = 0; n < 128; ++n) {
      float xi = sxi[ti][n], yi = syi[ti][n], tii = sti[ti][n];
      float xj = sxj[tj][n], yj = syj[tj][n], tjj = stj[tj][n];
      float ddx = xj - xi, ddy = yj - yi;
      float df = ddx*ddx + ddy*ddy;
      float sx = 0.5f*(xi + xj), sy = 0.5f*(yi + yj);
      float af = sx*sx + sy*sy;
      float g1 = __expf(df*(-0.5f/128.0f))*C1;
      float h  = __expf(af*(-0.5f/96.0f))*C2;
      aV += g1 + g1*h;
      aM += tii*tjj;
    }
  }
  if (i < 100 && j < 100) {
    double val = (i == j) ? 1e-10 : ((double)aV - (double)aM);
    out[OUT_A + (img*MM + i)*MM + j] = (float)val;
    ad[(img*MM + i)*MM + j] = val;
    if (it != jt) {                     // mirror (diag tiles cover both in-tile)
      out[OUT_A + (img*MM + j)*MM + i] = (float)val;
      ad[(img*MM + j)*MM + i] = val;
    }
  }
}

// ============ K5: fused GJ inversion (blocks 0..7) + m output (blocks 8..) ============
__global__ __launch_bounds__(256)
void k_inv_m(const double* __restrict__ ad,
             const double* __restrict__ vm,
             const float* __restrict__ pts,
             float* __restrict__ out) {
  __shared__ double S[128*17];          // 17,408 B
  __shared__ double Pr[16*113];         // 14,464 B
  __shared__ double svm[112];           //    896 B  -> total 32,768 B
  if (blockIdx.x >= BB) {
    // ---- m part: 4 elems per thread; pure streaming float4 writes
    int t = (int)(blockIdx.x - BB)*256 + threadIdx.x;
    int e = t << 2;
    int img = e >> 21;
    int rem = e & ((1 << 21) - 1);
    int n = rem >> 12;
    int g = rem & 4095;
    int iy = g >> 6, ix = g & 63;       // e%4==0 -> ix%4==0
    const float CM = (float)(1.0/(2.0*M_PI*128.0));
    float x = pts[(img*NN + n)*2 + 0];
    float y = pts[(img*NN + n)*2 + 1];
    float dy = y - (8.0f*iy + 4.0f);
    float ey = __expf(dy*dy*(-0.5f/128.0f));
    float4 r;
    {
      float dx0 = x - (8.0f*ix + 4.0f);
      float dx1 = x - (8.0f*(ix+1) + 4.0f);
      float dx2 = x - (8.0f*(ix+2) + 4.0f);
      float dx3 = x - (8.0f*(ix+3) + 4.0f);
      r.x = ey*__expf(dx0*dx0*(-0.5f/128.0f))*CM;
      r.y = ey*__expf(dx1*dx1*(-0.5f/128.0f))*CM;
      r.z = ey*__expf(dx2*dx2*(-0.5f/128.0f))*CM;
      r.w = ey*__expf(dx3*dx3*(-0.5f/128.0f))*CM;
    }
    *reinterpret_cast<float4*>(&out[OUT_M + e]) = r;
    return;
  }
  // ---- inversion part: no-pivot blocked fp64 GJ (SPD), Bm = Dv^{-1} - (A+Dv)^{-1}
  int img = blockIdx.x;
  int tx = threadIdx.x & 15, ty = threadIdx.x >> 4;   // ty in [0,16)
  double C[7][7];
  if (threadIdx.x < 100) svm[threadIdx.x] = vm[img*MM + threadIdx.x];
  // init C = A + diag(vM); rows/cols >= 100 -> 0
  #pragma unroll
  for (int a = 0; a < 7; ++a) {
    int r = ty + 16*a;
    #pragma unroll
    for (int b = 0; b < 7; ++b) {
      int j = tx + 16*b;
      double v2 = (r < 100 && j < 100) ? ad[(img*MM + r)*MM + j] : 0.0;
      if (r == j && r < 100) v2 += vm[img*MM + r];
      C[a][b] = v2;
    }
  }
  for (int p = 0; p < 7; ++p) {
    int k0 = p*16;
    int nbp = (p == 6) ? 4 : 16;
    // ---- P1: stage panel-col strip S + panel rows Pr (phase-start values)
    #pragma unroll
    for (int a = 0; a < 7; ++a) {
      int r = ty + 16*a;
      double val = 0.0;
      #pragma unroll
      for (int b = 0; b < 7; ++b) if (b == p) val = C[a][b];
      S[r*17 + tx] = (r < 100 && tx < nbp) ? val : 0.0;
    }
    {
      // panel rows k0..k0+15 are owned by row-block a==p: thread (ty,tx) holds
      // C[p][b] = element (k0+ty, tx+16b). Static-index extract via predication.
      double pv[7];
      #pragma unroll
      for (int b = 0; b < 7; ++b) pv[b] = 0.0;
      #pragma unroll
      for (int a = 0; a < 7; ++a) {
        #pragma unroll
        for (int b = 0; b < 7; ++b) if (a == p) pv[b] = C[a][b];
      }
      #pragma unroll
      for (int b = 0; b < 7; ++b) Pr[ty*113 + tx + 16*b] = pv[b];
    }
    __syncthreads();                                   // B1
    // ---- P2: wave 0 register-resident strip factorization (no pivoting)
    if (threadIdx.x < 64) {
      int lane = threadIdx.x;
      double P0[16], P1[16];
      #pragma unroll
      for (int c = 0; c < 16; ++c) {
        P0[c] = S[lane*17 + c];
        P1[c] = (lane + 64 < 112) ? S[(lane + 64)*17 + c] : 0.0;
      }
      #pragma unroll
      for (int kk = 0; kk < 16; ++kk) {
        if (kk < nbp) {
          int kg = k0 + kk;
          int r1 = lane + 64;
          bool khigh = kg >= 64; int kl = kg & 63;
          double pivinv = 1.0 / dbl_readlane(khigh ? P1[kk] : P0[kk], kl);
          double pr[16];
          #pragma unroll
          for (int c = 0; c < 16; ++c) {
            double pv = dbl_readlane(khigh ? P1[c] : P0[c], kl);
            pr[c] = (c == kk) ? pivinv : pv*pivinv;
          }
          {
            double f = P0[kk];
            if (lane == kg) {
              #pragma unroll
              for (int c = 0; c < 16; ++c) P0[c] = pr[c];
            } else {
              #pragma unroll
              for (int c = 0; c < 16; ++c) P0[c] = ((c == kk) ? 0.0 : P0[c]) - f*pr[c];
            }
          }
          {
            double f = P1[kk];
            if (r1 == kg) {
              #pragma unroll
              for (int c = 0; c < 16; ++c) P1[c] = pr[c];
            } else {
              #pragma unroll
              for (int c = 0; c < 16; ++c) P1[c] = ((c == kk) ? 0.0 : P1[c]) - f*pr[c];
            }
          }
        }
      }
      #pragma unroll
      for (int c = 0; c < 16; ++c) {
        S[lane*17 + c] = P0[c];
        if (lane + 64 < 112) S[(lane + 64)*17 + c] = P1[c];
      }
    }
    __syncthreads();                                   // B2
    // ---- P3: mask C in REGISTERS (panel rows/col + r>=100 zeroed),
    //          trailing rank-16 update from Pr, panel-col writeback from S
    #pragma unroll
    for (int a = 0; a < 7; ++a) {
      int r = ty + 16*a;
      bool prow_ = (r >= k0) && (r < k0 + 16);
      #pragma unroll
      for (int b = 0; b < 7; ++b) {
        if (r >= 100 || b == p || prow_) C[a][b] = 0.0;
      }
    }
    #pragma unroll 4
    for (int t = 0; t < 16; ++t) {
      bool tok = (t < nbp);
      double bt[7], sa[7];
      #pragma unroll
      for (int b = 0; b < 7; ++b) bt[b] = tok ? Pr[t*113 + tx + 16*b] : 0.0;
      #pragma unroll
      for (int a = 0; a < 7; ++a) sa[a] = S[(ty + 16*a)*17 + t];
      #pragma unroll
      for (int a = 0; a < 7; ++a)
        #pragma unroll
        for (int b = 0; b < 7; ++b) C[a][b] += sa[a]*bt[b];
    }
    #pragma unroll
    for (int a = 0; a < 7; ++a) {
      int r = ty + 16*a;
      double sval = S[r*17 + tx];
      #pragma unroll
      for (int b = 0; b < 7; ++b) if (b == p) C[a][b] = sval;
    }
    __syncthreads();                                   // B3 (WAR on S/Pr)
  }
  // Bm = Dv^{-1} - X
  #pragma unroll
  for (int a = 0; a < 7; ++a) {
    int r = ty + 16*a; if (r >= 100) continue;
    double dinv = 1.0 / svm[r];
    #pragma unroll
    for (int b = 0; b < 7; ++b) {
      int c = tx + 16*b; if (c >= 100) continue;
      double val = ((c == r) ? dinv : 0.0) - C[a][b];
      out[OUT_B + (img*MM + r)*MM + c] = (float)val;
    }
  }
}

extern "C" void kernel_launch(void* const* d_in, const int* in_sizes, int n_in,
                              void* d_out, int out_size, void* d_ws, size_t ws_size,
                              hipStream_t stream) {
  const float* pts = (const float*)d_in[0];
  float* out = (float*)d_out;
  char* ws = (char*)d_ws;
  double* vd  = (double*)(ws + OFF_VD);
  double* vmd = (double*)(ws + OFF_VM);
  double* ad  = (double*)(ws + OFF_AD);
  int* minds = (int*)(ws + OFF_MIND);

  hipLaunchKernelGGL(k_vpart, dim3(BB*16), dim3(256), 0, stream, pts, vd);
  hipLaunchKernelGGL(k_select, dim3(BB), dim3(256), 0, stream, vd, out, minds, vmd);
  hipLaunchKernelGGL(k_A, dim3(BB*28), dim3(256), 0, stream, pts, minds, out, ad);
  hipLaunchKernelGGL(k_inv_m, dim3(BB + (BB*NN*GG)/(256*4)), dim3(256), 0, stream,
                     ad, vmd, pts, out);
}

// Round 6
// 235.466 us; speedup vs baseline: 1.2924x; 1.0004x over previous
//
#include <hip/hip_runtime.h>
#include <math.h>

#ifndef M_PI
#define M_PI 3.14159265358979323846
#endif

#define BB 8
#define NN 512
#define KK 64
#define GG 4096
#define MM 100

// ---------------- workspace layout (byte offsets) ----------------
#define SZ_VD    (BB*GG*8u)
#define OFF_VD   0u
#define SZ_VM    (BB*MM*8u)
#define OFF_VM   (OFF_VD + SZ_VD)
#define SZ_AD    (BB*MM*MM*8u)
#define OFF_AD   (OFF_VM + SZ_VM)
#define OFF_MIND (OFF_AD + SZ_AD)

// ---------------- output layout (float element offsets) ----------------
#define OUT_M  0
#define OUT_V  (BB*NN*GG)               // 16,777,216
#define OUT_A  (OUT_V + BB*GG)          // 16,809,984
#define OUT_B  (OUT_A + BB*MM*MM)      // 16,889,984
#define OUT_MI (OUT_B + BB*MM*MM)      // 16,969,984

// ---------------- m-unit allocation across dispatches ----------------
// The m output (16384 units of 256 thr x float4) is the only dependency-free
// bulk work in the pipeline. r3 put it all in the last dispatch; that left
// vpart/select/A running on an idle machine (low DVFS clocks). Spread it:
#define MU_VP 2048            // with k_vpart   (units 0..2047)
#define MU_SE 1024            // with k_select  (units 2048..3071)
#define MU_KA 1024            // with k_A       (units 3072..4095)
#define MU_IV 12288           // with k_inv_m   (units 4096..16383)

__device__ __forceinline__ void m_one_unit(const float* __restrict__ pts,
                                           float* __restrict__ out, int u) {
  int t = u*256 + (int)threadIdx.x;
  int e = t << 2;
  int img = e >> 21;
  int rem = e & ((1 << 21) - 1);
  int n = rem >> 12;
  int g = rem & 4095;
  int iy = g >> 6, ix = g & 63;         // e%4==0 -> ix%4==0
  const float CM = (float)(1.0/(2.0*M_PI*128.0));
  float x = pts[(img*NN + n)*2 + 0];
  float y = pts[(img*NN + n)*2 + 1];
  float dy = y - (8.0f*iy + 4.0f);
  float ey = __expf(dy*dy*(-0.5f/128.0f));
  float4 r;
  float dx0 = x - (8.0f*ix + 4.0f);
  float dx1 = x - (8.0f*(ix+1) + 4.0f);
  float dx2 = x - (8.0f*(ix+2) + 4.0f);
  float dx3 = x - (8.0f*(ix+3) + 4.0f);
  r.x = ey*__expf(dx0*dx0*(-0.5f/128.0f))*CM;
  r.y = ey*__expf(dx1*dx1*(-0.5f/128.0f))*CM;
  r.z = ey*__expf(dx2*dx2*(-0.5f/128.0f))*CM;
  r.w = ey*__expf(dx3*dx3*(-0.5f/128.0f))*CM;
  *reinterpret_cast<float4*>(&out[OUT_M + e]) = r;
}

__device__ __forceinline__ double dbl_readlane(double v, int l) {
  long long b = __double_as_longlong(v);
  int lo = __builtin_amdgcn_readlane((int)(unsigned)((unsigned long long)b & 0xffffffffull), l);
  int hi = __builtin_amdgcn_readlane((int)(unsigned)((unsigned long long)b >> 32), l);
  return __longlong_as_double((long long)(((unsigned long long)(unsigned)hi << 32) | (unsigned)lo));
}

// ============ K2: v — two 64x64 matmuls, FULL-K + background m blocks ============
__global__ __launch_bounds__(256) void k_vpart(const float* __restrict__ pts,
                                               double* __restrict__ vd,
                                               float* __restrict__ out) {
  __shared__ double sEy2[16][66], sEx2[16][66], sEy3[16][66], sEx3[16][66];
  __shared__ float px[NN], py[NN];
  int bid = blockIdx.x;                 // img*16 + tile  |  m blocks
  if (bid >= BB*16) { m_one_unit(pts, out, bid - BB*16 + 0); return; }
  int tile = bid & 15;
  int img = bid >> 4;
  int iy0 = (tile >> 2) << 4;
  int ix0 = (tile & 3) << 4;
  int tx = threadIdx.x & 15, ty = threadIdx.x >> 4;
  for (int s = threadIdx.x; s < NN; s += 256) {
    px[s] = pts[(img*NN + s)*2 + 0];
    py[s] = pts[(img*NN + s)*2 + 1];
  }
  double aV = 0.0, aM = 0.0;
  for (int kc = 0; kc < 8; ++kc) {
    int nb = kc << 6;
    __syncthreads();                    // WAR on LDS (and px/py ready on kc=0)
    for (int s = threadIdx.x; s < 16*64; s += 256) {
      int row = s >> 6, n = s & 63;
      int nn = nb + n;
      double y = (double)py[nn];
      double cy = 8.0*(iy0 + row) + 4.0;
      double dy = y - cy, dy2 = dy*dy;
      sEy2[row][n] = exp(dy2*(-0.5/96.0));
      sEy3[row][n] = exp(dy2*(-1.0/128.0));
      double x = (double)px[nn];
      double cx = 8.0*(ix0 + row) + 4.0;
      double dx = x - cx, dx2 = dx*dx;
      sEx2[row][n] = exp(dx2*(-0.5/96.0));
      sEx3[row][n] = exp(dx2*(-1.0/128.0));
    }
    __syncthreads();
    #pragma unroll 8
    for (int n = 0; n < 64; ++n) {
      aV += sEy2[ty][n]*sEx2[tx][n];
      aM += sEy3[ty][n]*sEx3[tx][n];
    }
  }
  const double CTV = 1.0/((2.0*M_PI*96.0)*(2.0*M_PI*128.0));
  const double CM2 = 1.0/((2.0*M_PI*128.0)*(2.0*M_PI*128.0));
  vd[img*GG + (iy0 + ty)*KK + ix0 + tx] = CTV*aV - CM2*aM;
}

// ---------------- bitonic sort of 128 ints ascending (shared array) ----------------
__device__ __forceinline__ void bitonic128(int* a, int tid) {
  for (int kk = 2; kk <= 128; kk <<= 1)
    for (int jj = kk >> 1; jj > 0; jj >>= 1) {
      if (tid < 128) {
        int p = tid ^ jj;
        if (p > tid) {
          int x = a[tid], y = a[p];
          bool up = ((tid & kk) == 0);
          if (up ? (x > y) : (x < y)) { a[tid] = y; a[p] = x; }
        }
      }
      __syncthreads();
    }
}

// ============ K3: top-100 radix select + background m blocks ============
__global__ __launch_bounds__(256) void k_select(const double* __restrict__ vd,
                                                float* __restrict__ out,
                                                int* __restrict__ minds,
                                                double* __restrict__ vm,
                                                const float* __restrict__ pts) {
  __shared__ unsigned long long ku[GG];        // 32 KB sortable keys
  __shared__ unsigned int hist4[4][256];       // per-wave histogram copies
  __shared__ unsigned int suf[257];            // suffix sums (+guard)
  __shared__ unsigned long long sPrefPlaced;   // chosen high bits, in place
  __shared__ unsigned long long sMaskHi;       // mask of decided bits
  __shared__ unsigned int sRem, sPickB, sPickRem, sCGt, sCEq;
  __shared__ int sel[128];
  __shared__ int tie[128];
  int img = blockIdx.x;
  if (img >= BB) { m_one_unit(pts, out, img - BB + MU_VP); return; }
  int tid = threadIdx.x;
  int wv = tid >> 6;
  // load, emit v output, build monotonic keys (desc v == desc unsigned key)
  for (int t = 0; t < 16; ++t) {
    int g = t*256 + tid;                       // consecutive lanes -> consecutive addrs
    double v = vd[img*GG + g];
    out[OUT_V + img*GG + g] = (float)fmax(v, 1e-6);
    long long u = __double_as_longlong(v);
    unsigned long long k = (u < 0) ? ~(unsigned long long)u
                                   : ((unsigned long long)u | 0x8000000000000000ull);
    ku[g] = k;
  }
  if (tid == 0) {
    sRem = 100; sPrefPlaced = 0ull; sMaskHi = 0ull;
    sCGt = 0; sCEq = 0; suf[256] = 0;
  }
  // ---- 8 radix passes, MSB first ----
  for (int shift = 56; shift >= 0; shift -= 8) {
    for (int c = 0; c < 4; ++c) hist4[c][tid] = 0;
    __syncthreads();                            // ku ready / hist zeroed / state stable
    unsigned long long maskHi = sMaskHi, prefP = sPrefPlaced;
    for (int t = 0; t < 16; ++t) {
      int g = t*256 + tid;
      unsigned long long k = ku[g];
      if ((k & maskHi) == prefP) {
        unsigned d = (unsigned)((k >> shift) & 255ull);
        atomicAdd(&hist4[wv][d], 1u);
      }
    }
    __syncthreads();
    suf[tid] = hist4[0][tid] + hist4[1][tid] + hist4[2][tid] + hist4[3][tid];
    __syncthreads();
    for (int off = 1; off < 256; off <<= 1) {   // Hillis-Steele suffix sum
      unsigned add = (tid + off < 256) ? suf[tid + off] : 0u;
      __syncthreads();
      suf[tid] += add;
      __syncthreads();
    }
    unsigned rem = sRem;
    unsigned sgt = (tid < 255) ? suf[tid + 1] : 0u;
    if (suf[tid] >= rem && sgt < rem) { sPickB = (unsigned)tid; sPickRem = rem - sgt; }
    __syncthreads();
    if (tid == 0) {
      sPrefPlaced |= ((unsigned long long)sPickB) << shift;
      sMaskHi     |= (255ull << shift);
      sRem = sPickRem;
    }
    __syncthreads();
  }
  // ---- collect: all k > T, plus r smallest-index ties (k == T) ----
  unsigned long long T = sPrefPlaced;           // exact 100th-largest key
  for (int t = 0; t < 16; ++t) {
    int g = t*256 + tid;
    unsigned long long k = ku[g];
    if (k > T) {
      unsigned p = atomicAdd(&sCGt, 1u);        // p <= 98 always (count < 100)
      sel[p] = g;
    } else if (k == T) {
      unsigned p = atomicAdd(&sCEq, 1u);
      if (p < 128) tie[p] = g;                  // >128 exact-equal boundary values:
    }                                           // pathological, not hit by real data
  }
  __syncthreads();
  unsigned cgt = sCGt, ceq = sCEq, r = sRem;    // cgt + r == 100, 1 <= r <= ceq
  if (tid < 128 && tid >= (int)((ceq < 128u) ? ceq : 128u)) tie[tid] = 0x7fffffff;
  __syncthreads();
  bitonic128(tie, tid);                          // ties ascending by index
  if (tid < (int)r) sel[cgt + tid] = tie[tid];   // take r smallest-index ties
  if (tid >= MM && tid < 128) sel[tid] = 0x7fffffff;
  __syncthreads();
  bitonic128(sel, tid);                          // final Minds ascending
  if (tid < MM) {
    int mi = sel[tid];
    minds[img*MM + tid] = mi;
    out[OUT_MI + img*MM + tid] = (float)mi;      // whole out buffer is float32
    vm[img*MM + tid] = fmax(vd[img*GG + mi], 1e-6) + 1e-10;
  }
}

// ============ K4: assemble A — SYMMETRIC tiles + background m blocks ============
__global__ __launch_bounds__(256) void k_A(const float* __restrict__ pts,
                                           const int* __restrict__ minds,
                                           float* __restrict__ out, double* __restrict__ ad) {
  __shared__ float sxi[16][130], syi[16][130], sti[16][130];
  __shared__ float sxj[16][130], syj[16][130], stj[16][130];
  __shared__ float px[NN], py[NN];
  __shared__ float cxi[16], cyi[16], cxj[16], cyj[16];
  int bid = blockIdx.x;                 // img*28 + tri-tile  |  m blocks
  if (bid >= BB*28) { m_one_unit(pts, out, bid - BB*28 + MU_VP + MU_SE); return; }
  int img = bid / 28;
  int tile = bid - img*28;
  int it = 0, trem = tile;
  while (trem >= 7 - it) { trem -= 7 - it; ++it; }
  int jt = it + trem;
  int i0 = it*16, j0 = jt*16;
  int tj = threadIdx.x & 15, ti = threadIdx.x >> 4;
  int i = i0 + ti, j = j0 + tj;
  const float CM = (float)(1.0/(2.0*M_PI*128.0));
  const float C1 = (float)(1.0/(2.0*M_PI*128.0));   // g1 scale (2*pi*2*sigma2)
  const float C2 = (float)(1.0/(2.0*M_PI*96.0));    // h scale (2*pi*s2)
  for (int s = threadIdx.x; s < NN; s += 256) {
    px[s] = pts[(img*NN + s)*2 + 0];
    py[s] = pts[(img*NN + s)*2 + 1];
  }
  if (threadIdx.x < 16) {
    int gi = i0 + (int)threadIdx.x; if (gi > 99) gi = 99;
    int mi = minds[img*MM + gi];
    cxi[threadIdx.x] = 8.0f*(mi & 63) + 4.0f;
    cyi[threadIdx.x] = 8.0f*(mi >> 6) + 4.0f;
  } else if (threadIdx.x < 32) {
    int r = (int)threadIdx.x - 16;
    int gj = j0 + r; if (gj > 99) gj = 99;
    int mj = minds[img*MM + gj];
    cxj[r] = 8.0f*(mj & 63) + 4.0f;
    cyj[r] = 8.0f*(mj >> 6) + 4.0f;
  }
  float aV = 0.0f, aM = 0.0f;
  for (int nc = 0; nc < NN; nc += 128) {
    __syncthreads();
    for (int s = threadIdx.x; s < 16*128; s += 256) {
      int row = s >> 7, n = s & 127;
      float x = px[nc + n], y = py[nc + n];
      float fxi = x - cxi[row], fyi = y - cyi[row];
      sxi[row][n] = fxi; syi[row][n] = fyi;
      sti[row][n] = __expf((fxi*fxi + fyi*fyi)*(-0.5f/128.0f))*CM;
      float fxj = x - cxj[row], fyj = y - cyj[row];
      sxj[row][n] = fxj; syj[row][n] = fyj;
      stj[row][n] = __expf((fxj*fxj + fyj*fyj)*(-0.5f/128.0f))*CM;
    }
    __syncthreads();
    #pragma unroll 4
    for (int n = 0; n < 128; ++n) {
      float xi = sxi[ti][n], yi = syi[ti][n], tii = sti[ti][n];
      float xj = sxj[tj][n], yj = syj[tj][n], tjj = stj[tj][n];
      float ddx = xj - xi, ddy = yj - yi;
      float df = ddx*ddx + ddy*ddy;
      float sx = 0.5f*(xi + xj), sy = 0.5f*(yi + yj);
      float af = sx*sx + sy*sy;
      float g1 = __expf(df*(-0.5f/128.0f))*C1;
      float h  = __expf(af*(-0.5f/96.0f))*C2;
      aV += g1 + g1*h;
      aM += tii*tjj;
    }
  }
  if (i < 100 && j < 100) {
    double val = (i == j) ? 1e-10 : ((double)aV - (double)aM);
    out[OUT_A + (img*MM + i)*MM + j] = (float)val;
    ad[(img*MM + i)*MM + j] = val;
    if (it != jt) {                     // mirror (diag tiles cover both in-tile)
      out[OUT_A + (img*MM + j)*MM + i] = (float)val;
      ad[(img*MM + j)*MM + i] = val;
    }
  }
}

// ============ K5: fused GJ inversion (blocks 0..7) + remaining m blocks ============
__global__ __launch_bounds__(256)
void k_inv_m(const double* __restrict__ ad,
             const double* __restrict__ vm,
             const float* __restrict__ pts,
             float* __restrict__ out) {
  __shared__ double S[128*17];          // 17,408 B
  __shared__ double Pr[16*113];         // 14,464 B
  __shared__ double svm[112];           //    896 B  -> total 32,768 B
  if (blockIdx.x >= BB) {
    m_one_unit(pts, out, (int)blockIdx.x - BB + MU_VP + MU_SE + MU_KA);
    return;
  }
  // ---- inversion part: no-pivot blocked fp64 GJ (SPD), Bm = Dv^{-1} - (A+Dv)^{-1}
  int img = blockIdx.x;
  int tx = threadIdx.x & 15, ty = threadIdx.x >> 4;   // ty in [0,16)
  double C[7][7];
  if (threadIdx.x < 100) svm[threadIdx.x] = vm[img*MM + threadIdx.x];
  // init C = A + diag(vM); rows/cols >= 100 -> 0
  #pragma unroll
  for (int a = 0; a < 7; ++a) {
    int r = ty + 16*a;
    #pragma unroll
    for (int b = 0; b < 7; ++b) {
      int j = tx + 16*b;
      double v2 = (r < 100 && j < 100) ? ad[(img*MM + r)*MM + j] : 0.0;
      if (r == j && r < 100) v2 += vm[img*MM + r];
      C[a][b] = v2;
    }
  }
  for (int p = 0; p < 7; ++p) {
    int k0 = p*16;
    int nbp = (p == 6) ? 4 : 16;
    // ---- P1: stage panel-col strip S + panel rows Pr (phase-start values)
    #pragma unroll
    for (int a = 0; a < 7; ++a) {
      int r = ty + 16*a;
      double val = 0.0;
      #pragma unroll
      for (int b = 0; b < 7; ++b) if (b == p) val = C[a][b];
      S[r*17 + tx] = (r < 100 && tx < nbp) ? val : 0.0;
    }
    {
      // panel rows k0..k0+15 are owned by row-block a==p: thread (ty,tx) holds
      // C[p][b] = element (k0+ty, tx+16b). Static-index extract via predication.
      double pv[7];
      #pragma unroll
      for (int b = 0; b < 7; ++b) pv[b] = 0.0;
      #pragma unroll
      for (int a = 0; a < 7; ++a) {
        #pragma unroll
        for (int b = 0; b < 7; ++b) if (a == p) pv[b] = C[a][b];
      }
      #pragma unroll
      for (int b = 0; b < 7; ++b) Pr[ty*113 + tx + 16*b] = pv[b];
    }
    __syncthreads();                                   // B1
    // ---- P2: wave 0 register-resident strip factorization (no pivoting)
    if (threadIdx.x < 64) {
      int lane = threadIdx.x;
      double P0[16], P1[16];
      #pragma unroll
      for (int c = 0; c < 16; ++c) {
        P0[c] = S[lane*17 + c];
        P1[c] = (lane + 64 < 112) ? S[(lane + 64)*17 + c] : 0.0;
      }
      #pragma unroll
      for (int kk = 0; kk < 16; ++kk) {
        if (kk < nbp) {
          int kg = k0 + kk;
          int r1 = lane + 64;
          bool khigh = kg >= 64; int kl = kg & 63;
          double pivinv = 1.0 / dbl_readlane(khigh ? P1[kk] : P0[kk], kl);
          double pr[16];
          #pragma unroll
          for (int c = 0; c < 16; ++c) {
            double pv = dbl_readlane(khigh ? P1[c] : P0[c], kl);
            pr[c] = (c == kk) ? pivinv : pv*pivinv;
          }
          {
            double f = P0[kk];
            if (lane == kg) {
              #pragma unroll
              for (int c = 0; c < 16; ++c) P0[c] = pr[c];
            } else {
              #pragma unroll
              for (int c = 0; c < 16; ++c) P0[c] = ((c == kk) ? 0.0 : P0[c]) - f*pr[c];
            }
          }
          {
            double f = P1[kk];
            if (r1 == kg) {
              #pragma unroll
              for (int c = 0; c < 16; ++c) P1[c] = pr[c];
            } else {
              #pragma unroll
              for (int c = 0; c < 16; ++c) P1[c] = ((c == kk) ? 0.0 : P1[c]) - f*pr[c];
            }
          }
        }
      }
      #pragma unroll
      for (int c = 0; c < 16; ++c) {
        S[lane*17 + c] = P0[c];
        if (lane + 64 < 112) S[(lane + 64)*17 + c] = P1[c];
      }
    }
    __syncthreads();                                   // B2
    // ---- P3: mask C in REGISTERS (panel rows/col + r>=100 zeroed),
    //          trailing rank-16 update from Pr, panel-col writeback from S
    #pragma unroll
    for (int a = 0; a < 7; ++a) {
      int r = ty + 16*a;
      bool prow_ = (r >= k0) && (r < k0 + 16);
      #pragma unroll
      for (int b = 0; b < 7; ++b) {
        if (r >= 100 || b == p || prow_) C[a][b] = 0.0;
      }
    }
    #pragma unroll 4
    for (int t = 0; t < 16; ++t) {
      bool tok = (t < nbp);
      double bt[7], sa[7];
      #pragma unroll
      for (int b = 0; b < 7; ++b) bt[b] = tok ? Pr[t*113 + tx + 16*b] : 0.0;
      #pragma unroll
      for (int a = 0; a < 7; ++a) sa[a] = S[(ty + 16*a)*17 + t];
      #pragma unroll
      for (int a = 0; a < 7; ++a)
        #pragma unroll
        for (int b = 0; b < 7; ++b) C[a][b] += sa[a]*bt[b];
    }
    #pragma unroll
    for (int a = 0; a < 7; ++a) {
      int r = ty + 16*a;
      double sval = S[r*17 + tx];
      #pragma unroll
      for (int b = 0; b < 7; ++b) if (b == p) C[a][b] = sval;
    }
    __syncthreads();                                   // B3 (WAR on S/Pr)
  }
  // Bm = Dv^{-1} - X
  #pragma unroll
  for (int a = 0; a < 7; ++a) {
    int r = ty + 16*a; if (r >= 100) continue;
    double dinv = 1.0 / svm[r];
    #pragma unroll
    for (int b = 0; b < 7; ++b) {
      int c = tx + 16*b; if (c >= 100) continue;
      double val = ((c == r) ? dinv : 0.0) - C[a][b];
      out[OUT_B + (img*MM + r)*MM + c] = (float)val;
    }
  }
}

extern "C" void kernel_launch(void* const* d_in, const int* in_sizes, int n_in,
                              void* d_out, int out_size, void* d_ws, size_t ws_size,
                              hipStream_t stream) {
  const float* pts = (const float*)d_in[0];
  float* out = (float*)d_out;
  char* ws = (char*)d_ws;
  double* vd  = (double*)(ws + OFF_VD);
  double* vmd = (double*)(ws + OFF_VM);
  double* ad  = (double*)(ws + OFF_AD);
  int* minds = (int*)(ws + OFF_MIND);

  hipLaunchKernelGGL(k_vpart, dim3(BB*16 + MU_VP), dim3(256), 0, stream, pts, vd, out);
  hipLaunchKernelGGL(k_select, dim3(BB + MU_SE), dim3(256), 0, stream, vd, out, minds, vmd, pts);
  hipLaunchKernelGGL(k_A, dim3(BB*28 + MU_KA), dim3(256), 0, stream, pts, minds, out, ad);
  hipLaunchKernelGGL(k_inv_m, dim3(BB + MU_IV), dim3(256), 0, stream, ad, vmd, pts, out);
}

// Round 7
// 230.559 us; speedup vs baseline: 1.3199x; 1.0213x over previous
//
#include <hip/hip_runtime.h>
#include <math.h>

#ifndef M_PI
#define M_PI 3.14159265358979323846
#endif

#define BB 8
#define NN 512
#define KK 64
#define GG 4096
#define MM 100

// ---------------- workspace layout (byte offsets) ----------------
#define SZ_VD    (BB*GG*8u)
#define OFF_VD   0u
#define SZ_VM    (BB*MM*8u)
#define OFF_VM   (OFF_VD + SZ_VD)
#define SZ_AD    (BB*MM*MM*8u)
#define OFF_AD   (OFF_VM + SZ_VM)
#define OFF_MIND (OFF_AD + SZ_AD)

// ---------------- output layout (float element offsets) ----------------
#define OUT_M  0
#define OUT_V  (BB*NN*GG)               // 16,777,216
#define OUT_A  (OUT_V + BB*GG)          // 16,809,984
#define OUT_B  (OUT_A + BB*MM*MM)      // 16,889,984
#define OUT_MI (OUT_B + BB*MM*MM)      // 16,969,984

// ---------------- m-unit allocation across dispatches ----------------
// m (16384 units of 256 thr x float4) is the only dependency-free bulk work.
// r6 evidence: stages absorb m-load without slowing (idle CUs), and k_inv_m's
// duration is pinned by the INVERSION, not by its m-share. With the fp32
// inversion (~45 us) the last dispatch's cover shrinks to ~29 MB to match.
#define MU_VP 4096            // with k_vpart   (units 0..4095)
#define MU_SE 2048            // with k_select  (units 4096..6143)
#define MU_KA 3072            // with k_A       (units 6144..9215)
#define MU_IV 7168            // with k_inv_m   (units 9216..16383)

__device__ __forceinline__ void m_one_unit(const float* __restrict__ pts,
                                           float* __restrict__ out, int u) {
  int t = u*256 + (int)threadIdx.x;
  int e = t << 2;
  int img = e >> 21;
  int rem = e & ((1 << 21) - 1);
  int n = rem >> 12;
  int g = rem & 4095;
  int iy = g >> 6, ix = g & 63;         // e%4==0 -> ix%4==0
  const float CM = (float)(1.0/(2.0*M_PI*128.0));
  float x = pts[(img*NN + n)*2 + 0];
  float y = pts[(img*NN + n)*2 + 1];
  float dy = y - (8.0f*iy + 4.0f);
  float ey = __expf(dy*dy*(-0.5f/128.0f));
  float4 r;
  float dx0 = x - (8.0f*ix + 4.0f);
  float dx1 = x - (8.0f*(ix+1) + 4.0f);
  float dx2 = x - (8.0f*(ix+2) + 4.0f);
  float dx3 = x - (8.0f*(ix+3) + 4.0f);
  r.x = ey*__expf(dx0*dx0*(-0.5f/128.0f))*CM;
  r.y = ey*__expf(dx1*dx1*(-0.5f/128.0f))*CM;
  r.z = ey*__expf(dx2*dx2*(-0.5f/128.0f))*CM;
  r.w = ey*__expf(dx3*dx3*(-0.5f/128.0f))*CM;
  *reinterpret_cast<float4*>(&out[OUT_M + e]) = r;
}

__device__ __forceinline__ float flt_readlane(float v, int l) {
  return __int_as_float(__builtin_amdgcn_readlane(__float_as_int(v), l));
}

// ============ K2: v — two 64x64 matmuls, FULL-K + background m blocks ============
__global__ __launch_bounds__(256) void k_vpart(const float* __restrict__ pts,
                                               double* __restrict__ vd,
                                               float* __restrict__ out) {
  __shared__ double sEy2[16][66], sEx2[16][66], sEy3[16][66], sEx3[16][66];
  __shared__ float px[NN], py[NN];
  int bid = blockIdx.x;                 // img*16 + tile  |  m blocks
  if (bid >= BB*16) { m_one_unit(pts, out, bid - BB*16 + 0); return; }
  int tile = bid & 15;
  int img = bid >> 4;
  int iy0 = (tile >> 2) << 4;
  int ix0 = (tile & 3) << 4;
  int tx = threadIdx.x & 15, ty = threadIdx.x >> 4;
  for (int s = threadIdx.x; s < NN; s += 256) {
    px[s] = pts[(img*NN + s)*2 + 0];
    py[s] = pts[(img*NN + s)*2 + 1];
  }
  double aV = 0.0, aM = 0.0;
  for (int kc = 0; kc < 8; ++kc) {
    int nb = kc << 6;
    __syncthreads();                    // WAR on LDS (and px/py ready on kc=0)
    for (int s = threadIdx.x; s < 16*64; s += 256) {
      int row = s >> 6, n = s & 63;
      int nn = nb + n;
      double y = (double)py[nn];
      double cy = 8.0*(iy0 + row) + 4.0;
      double dy = y - cy, dy2 = dy*dy;
      sEy2[row][n] = exp(dy2*(-0.5/96.0));
      sEy3[row][n] = exp(dy2*(-1.0/128.0));
      double x = (double)px[nn];
      double cx = 8.0*(ix0 + row) + 4.0;
      double dx = x - cx, dx2 = dx*dx;
      sEx2[row][n] = exp(dx2*(-0.5/96.0));
      sEx3[row][n] = exp(dx2*(-1.0/128.0));
    }
    __syncthreads();
    #pragma unroll 8
    for (int n = 0; n < 64; ++n) {
      aV += sEy2[ty][n]*sEx2[tx][n];
      aM += sEy3[ty][n]*sEx3[tx][n];
    }
  }
  const double CTV = 1.0/((2.0*M_PI*96.0)*(2.0*M_PI*128.0));
  const double CM2 = 1.0/((2.0*M_PI*128.0)*(2.0*M_PI*128.0));
  vd[img*GG + (iy0 + ty)*KK + ix0 + tx] = CTV*aV - CM2*aM;
}

// ---------------- bitonic sort of 128 ints ascending (shared array) ----------------
__device__ __forceinline__ void bitonic128(int* a, int tid) {
  for (int kk = 2; kk <= 128; kk <<= 1)
    for (int jj = kk >> 1; jj > 0; jj >>= 1) {
      if (tid < 128) {
        int p = tid ^ jj;
        if (p > tid) {
          int x = a[tid], y = a[p];
          bool up = ((tid & kk) == 0);
          if (up ? (x > y) : (x < y)) { a[tid] = y; a[p] = x; }
        }
      }
      __syncthreads();
    }
}

// ============ K3: top-100 radix select + background m blocks ============
__global__ __launch_bounds__(256) void k_select(const double* __restrict__ vd,
                                                float* __restrict__ out,
                                                int* __restrict__ minds,
                                                double* __restrict__ vm,
                                                const float* __restrict__ pts) {
  __shared__ unsigned long long ku[GG];        // 32 KB sortable keys
  __shared__ unsigned int hist4[4][256];       // per-wave histogram copies
  __shared__ unsigned int suf[257];            // suffix sums (+guard)
  __shared__ unsigned long long sPrefPlaced;   // chosen high bits, in place
  __shared__ unsigned long long sMaskHi;       // mask of decided bits
  __shared__ unsigned int sRem, sPickB, sPickRem, sCGt, sCEq;
  __shared__ int sel[128];
  __shared__ int tie[128];
  int img = blockIdx.x;
  if (img >= BB) { m_one_unit(pts, out, img - BB + MU_VP); return; }
  int tid = threadIdx.x;
  int wv = tid >> 6;
  // load, emit v output, build monotonic keys (desc v == desc unsigned key)
  for (int t = 0; t < 16; ++t) {
    int g = t*256 + tid;                       // consecutive lanes -> consecutive addrs
    double v = vd[img*GG + g];
    out[OUT_V + img*GG + g] = (float)fmax(v, 1e-6);
    long long u = __double_as_longlong(v);
    unsigned long long k = (u < 0) ? ~(unsigned long long)u
                                   : ((unsigned long long)u | 0x8000000000000000ull);
    ku[g] = k;
  }
  if (tid == 0) {
    sRem = 100; sPrefPlaced = 0ull; sMaskHi = 0ull;
    sCGt = 0; sCEq = 0; suf[256] = 0;
  }
  // ---- 8 radix passes, MSB first ----
  for (int shift = 56; shift >= 0; shift -= 8) {
    for (int c = 0; c < 4; ++c) hist4[c][tid] = 0;
    __syncthreads();                            // ku ready / hist zeroed / state stable
    unsigned long long maskHi = sMaskHi, prefP = sPrefPlaced;
    for (int t = 0; t < 16; ++t) {
      int g = t*256 + tid;
      unsigned long long k = ku[g];
      if ((k & maskHi) == prefP) {
        unsigned d = (unsigned)((k >> shift) & 255ull);
        atomicAdd(&hist4[wv][d], 1u);
      }
    }
    __syncthreads();
    suf[tid] = hist4[0][tid] + hist4[1][tid] + hist4[2][tid] + hist4[3][tid];
    __syncthreads();
    for (int off = 1; off < 256; off <<= 1) {   // Hillis-Steele suffix sum
      unsigned add = (tid + off < 256) ? suf[tid + off] : 0u;
      __syncthreads();
      suf[tid] += add;
      __syncthreads();
    }
    unsigned rem = sRem;
    unsigned sgt = (tid < 255) ? suf[tid + 1] : 0u;
    if (suf[tid] >= rem && sgt < rem) { sPickB = (unsigned)tid; sPickRem = rem - sgt; }
    __syncthreads();
    if (tid == 0) {
      sPrefPlaced |= ((unsigned long long)sPickB) << shift;
      sMaskHi     |= (255ull << shift);
      sRem = sPickRem;
    }
    __syncthreads();
  }
  // ---- collect: all k > T, plus r smallest-index ties (k == T) ----
  unsigned long long T = sPrefPlaced;           // exact 100th-largest key
  for (int t = 0; t < 16; ++t) {
    int g = t*256 + tid;
    unsigned long long k = ku[g];
    if (k > T) {
      unsigned p = atomicAdd(&sCGt, 1u);        // p <= 98 always (count < 100)
      sel[p] = g;
    } else if (k == T) {
      unsigned p = atomicAdd(&sCEq, 1u);
      if (p < 128) tie[p] = g;                  // >128 exact-equal boundary values:
    }                                           // pathological, not hit by real data
  }
  __syncthreads();
  unsigned cgt = sCGt, ceq = sCEq, r = sRem;    // cgt + r == 100, 1 <= r <= ceq
  if (tid < 128 && tid >= (int)((ceq < 128u) ? ceq : 128u)) tie[tid] = 0x7fffffff;
  __syncthreads();
  bitonic128(tie, tid);                          // ties ascending by index
  if (tid < (int)r) sel[cgt + tid] = tie[tid];   // take r smallest-index ties
  if (tid >= MM && tid < 128) sel[tid] = 0x7fffffff;
  __syncthreads();
  bitonic128(sel, tid);                          // final Minds ascending
  if (tid < MM) {
    int mi = sel[tid];
    minds[img*MM + tid] = mi;
    out[OUT_MI + img*MM + tid] = (float)mi;      // whole out buffer is float32
    vm[img*MM + tid] = fmax(vd[img*GG + mi], 1e-6) + 1e-10;
  }
}

// ============ K4: assemble A — SYMMETRIC tiles + background m blocks ============
__global__ __launch_bounds__(256) void k_A(const float* __restrict__ pts,
                                           const int* __restrict__ minds,
                                           float* __restrict__ out, double* __restrict__ ad) {
  __shared__ float sxi[16][130], syi[16][130], sti[16][130];
  __shared__ float sxj[16][130], syj[16][130], stj[16][130];
  __shared__ float px[NN], py[NN];
  __shared__ float cxi[16], cyi[16], cxj[16], cyj[16];
  int bid = blockIdx.x;                 // img*28 + tri-tile  |  m blocks
  if (bid >= BB*28) { m_one_unit(pts, out, bid - BB*28 + MU_VP + MU_SE); return; }
  int img = bid / 28;
  int tile = bid - img*28;
  int it = 0, trem = tile;
  while (trem >= 7 - it) { trem -= 7 - it; ++it; }
  int jt = it + trem;
  int i0 = it*16, j0 = jt*16;
  int tj = threadIdx.x & 15, ti = threadIdx.x >> 4;
  int i = i0 + ti, j = j0 + tj;
  const float CM = (float)(1.0/(2.0*M_PI*128.0));
  const float C1 = (float)(1.0/(2.0*M_PI*128.0));   // g1 scale (2*pi*2*sigma2)
  const float C2 = (float)(1.0/(2.0*M_PI*96.0));    // h scale (2*pi*s2)
  for (int s = threadIdx.x; s < NN; s += 256) {
    px[s] = pts[(img*NN + s)*2 + 0];
    py[s] = pts[(img*NN + s)*2 + 1];
  }
  if (threadIdx.x < 16) {
    int gi = i0 + (int)threadIdx.x; if (gi > 99) gi = 99;
    int mi = minds[img*MM + gi];
    cxi[threadIdx.x] = 8.0f*(mi & 63) + 4.0f;
    cyi[threadIdx.x] = 8.0f*(mi >> 6) + 4.0f;
  } else if (threadIdx.x < 32) {
    int r = (int)threadIdx.x - 16;
    int gj = j0 + r; if (gj > 99) gj = 99;
    int mj = minds[img*MM + gj];
    cxj[r] = 8.0f*(mj & 63) + 4.0f;
    cyj[r] = 8.0f*(mj >> 6) + 4.0f;
  }
  float aV = 0.0f, aM = 0.0f;
  for (int nc = 0; nc < NN; nc += 128) {
    __syncthreads();
    for (int s = threadIdx.x; s < 16*128; s += 256) {
      int row = s >> 7, n = s & 127;
      float x = px[nc + n], y = py[nc + n];
      float fxi = x - cxi[row], fyi = y - cyi[row];
      sxi[row][n] = fxi; syi[row][n] = fyi;
      sti[row][n] = __expf((fxi*fxi + fyi*fyi)*(-0.5f/128.0f))*CM;
      float fxj = x - cxj[row], fyj = y - cyj[row];
      sxj[row][n] = fxj; syj[row][n] = fyj;
      stj[row][n] = __expf((fxj*fxj + fyj*fyj)*(-0.5f/128.0f))*CM;
    }
    __syncthreads();
    #pragma unroll 4
    for (int n = 0; n < 128; ++n) {
      float xi = sxi[ti][n], yi = syi[ti][n], tii = sti[ti][n];
      float xj = sxj[tj][n], yj = syj[tj][n], tjj = stj[tj][n];
      float ddx = xj - xi, ddy = yj - yi;
      float df = ddx*ddx + ddy*ddy;
      float sx = 0.5f*(xi + xj), sy = 0.5f*(yi + yj);
      float af = sx*sx + sy*sy;
      float g1 = __expf(df*(-0.5f/128.0f))*C1;
      float h  = __expf(af*(-0.5f/96.0f))*C2;
      aV += g1 + g1*h;
      aM += tii*tjj;
    }
  }
  if (i < 100 && j < 100) {
    double val = (i == j) ? 1e-10 : ((double)aV - (double)aM);
    out[OUT_A + (img*MM + i)*MM + j] = (float)val;
    ad[(img*MM + i)*MM + j] = val;
    if (it != jt) {                     // mirror (diag tiles cover both in-tile)
      out[OUT_A + (img*MM + j)*MM + i] = (float)val;
      ad[(img*MM + j)*MM + i] = val;
    }
  }
}

// ============ K5: FP32 GJ inversion (blocks 0..7) + remaining m blocks ============
// r6 evidence: dispatch time pinned at 88 us by the fp64 inversion critical
// path (m-writes fully hidden). The jax reference inverts in FLOAT32 and our
// fp64 result matched it to 3e-7 relative => the system is well-conditioned
// and fp32 is safe (threshold 8110, current absmax 0.125). fp32 halves the
// serial P2 chain (1 readlane/value, ~3x cheaper divide, 2-cyc FMA) and
// halves LDS (32 KB -> 16 KB).
__global__ __launch_bounds__(256)
void k_inv_m(const double* __restrict__ ad,
             const double* __restrict__ vm,
             const float* __restrict__ pts,
             float* __restrict__ out) {
  __shared__ float S[128*17];           //  8,704 B
  __shared__ float Pr[16*113];          //  7,232 B
  __shared__ float svm[112];            //    448 B  -> total 16,384 B
  if (blockIdx.x >= BB) {
    m_one_unit(pts, out, (int)blockIdx.x - BB + MU_VP + MU_SE + MU_KA);
    return;
  }
  // ---- inversion part: no-pivot blocked fp32 GJ (SPD), Bm = Dv^{-1} - (A+Dv)^{-1}
  int img = blockIdx.x;
  int tx = threadIdx.x & 15, ty = threadIdx.x >> 4;   // ty in [0,16)
  float C[7][7];
  if (threadIdx.x < 100) svm[threadIdx.x] = (float)vm[img*MM + threadIdx.x];
  // init C = A + diag(vM); rows/cols >= 100 -> 0
  #pragma unroll
  for (int a = 0; a < 7; ++a) {
    int r = ty + 16*a;
    #pragma unroll
    for (int b = 0; b < 7; ++b) {
      int j = tx + 16*b;
      float v2 = (r < 100 && j < 100) ? (float)ad[(img*MM + r)*MM + j] : 0.0f;
      if (r == j && r < 100) v2 += (float)vm[img*MM + r];
      C[a][b] = v2;
    }
  }
  for (int p = 0; p < 7; ++p) {
    int k0 = p*16;
    int nbp = (p == 6) ? 4 : 16;
    // ---- P1: stage panel-col strip S + panel rows Pr (phase-start values)
    #pragma unroll
    for (int a = 0; a < 7; ++a) {
      int r = ty + 16*a;
      float val = 0.0f;
      #pragma unroll
      for (int b = 0; b < 7; ++b) if (b == p) val = C[a][b];
      S[r*17 + tx] = (r < 100 && tx < nbp) ? val : 0.0f;
    }
    {
      // panel rows k0..k0+15 are owned by row-block a==p: thread (ty,tx) holds
      // C[p][b] = element (k0+ty, tx+16b). Static-index extract via predication.
      float pv[7];
      #pragma unroll
      for (int b = 0; b < 7; ++b) pv[b] = 0.0f;
      #pragma unroll
      for (int a = 0; a < 7; ++a) {
        #pragma unroll
        for (int b = 0; b < 7; ++b) if (a == p) pv[b] = C[a][b];
      }
      #pragma unroll
      for (int b = 0; b < 7; ++b) Pr[ty*113 + tx + 16*b] = pv[b];
    }
    __syncthreads();                                   // B1
    // ---- P2: wave 0 register-resident strip factorization (no pivoting)
    if (threadIdx.x < 64) {
      int lane = threadIdx.x;
      float P0[16], P1[16];
      #pragma unroll
      for (int c = 0; c < 16; ++c) {
        P0[c] = S[lane*17 + c];
        P1[c] = (lane + 64 < 112) ? S[(lane + 64)*17 + c] : 0.0f;
      }
      #pragma unroll
      for (int kk = 0; kk < 16; ++kk) {
        if (kk < nbp) {
          int kg = k0 + kk;
          int r1 = lane + 64;
          bool khigh = kg >= 64; int kl = kg & 63;
          float pivinv = 1.0f / flt_readlane(khigh ? P1[kk] : P0[kk], kl);
          float pr[16];
          #pragma unroll
          for (int c = 0; c < 16; ++c) {
            float pv = flt_readlane(khigh ? P1[c] : P0[c], kl);
            pr[c] = (c == kk) ? pivinv : pv*pivinv;
          }
          {
            float f = P0[kk];
            if (lane == kg) {
              #pragma unroll
              for (int c = 0; c < 16; ++c) P0[c] = pr[c];
            } else {
              #pragma unroll
              for (int c = 0; c < 16; ++c) P0[c] = ((c == kk) ? 0.0f : P0[c]) - f*pr[c];
            }
          }
          {
            float f = P1[kk];
            if (r1 == kg) {
              #pragma unroll
              for (int c = 0; c < 16; ++c) P1[c] = pr[c];
            } else {
              #pragma unroll
              for (int c = 0; c < 16; ++c) P1[c] = ((c == kk) ? 0.0f : P1[c]) - f*pr[c];
            }
          }
        }
      }
      #pragma unroll
      for (int c = 0; c < 16; ++c) {
        S[lane*17 + c] = P0[c];
        if (lane + 64 < 112) S[(lane + 64)*17 + c] = P1[c];
      }
    }
    __syncthreads();                                   // B2
    // ---- P3: mask C in REGISTERS (panel rows/col + r>=100 zeroed),
    //          trailing rank-16 update from Pr, panel-col writeback from S
    #pragma unroll
    for (int a = 0; a < 7; ++a) {
      int r = ty + 16*a;
      bool prow_ = (r >= k0) && (r < k0 + 16);
      #pragma unroll
      for (int b = 0; b < 7; ++b) {
        if (r >= 100 || b == p || prow_) C[a][b] = 0.0f;
      }
    }
    #pragma unroll 4
    for (int t = 0; t < 16; ++t) {
      bool tok = (t < nbp);
      float bt[7], sa[7];
      #pragma unroll
      for (int b = 0; b < 7; ++b) bt[b] = tok ? Pr[t*113 + tx + 16*b] : 0.0f;
      #pragma unroll
      for (int a = 0; a < 7; ++a) sa[a] = S[(ty + 16*a)*17 + t];
      #pragma unroll
      for (int a = 0; a < 7; ++a)
        #pragma unroll
        for (int b = 0; b < 7; ++b) C[a][b] += sa[a]*bt[b];
    }
    #pragma unroll
    for (int a = 0; a < 7; ++a) {
      int r = ty + 16*a;
      float sval = S[r*17 + tx];
      #pragma unroll
      for (int b = 0; b < 7; ++b) if (b == p) C[a][b] = sval;
    }
    __syncthreads();                                   // B3 (WAR on S/Pr)
  }
  // Bm = Dv^{-1} - X
  #pragma unroll
  for (int a = 0; a < 7; ++a) {
    int r = ty + 16*a; if (r >= 100) continue;
    float dinv = 1.0f / svm[r];
    #pragma unroll
    for (int b = 0; b < 7; ++b) {
      int c = tx + 16*b; if (c >= 100) continue;
      float val = ((c == r) ? dinv : 0.0f) - C[a][b];
      out[OUT_B + (img*MM + r)*MM + c] = val;
    }
  }
}

extern "C" void kernel_launch(void* const* d_in, const int* in_sizes, int n_in,
                              void* d_out, int out_size, void* d_ws, size_t ws_size,
                              hipStream_t stream) {
  const float* pts = (const float*)d_in[0];
  float* out = (float*)d_out;
  char* ws = (char*)d_ws;
  double* vd  = (double*)(ws + OFF_VD);
  double* vmd = (double*)(ws + OFF_VM);
  double* ad  = (double*)(ws + OFF_AD);
  int* minds = (int*)(ws + OFF_MIND);

  hipLaunchKernelGGL(k_vpart, dim3(BB*16 + MU_VP), dim3(256), 0, stream, pts, vd, out);
  hipLaunchKernelGGL(k_select, dim3(BB + MU_SE), dim3(256), 0, stream, vd, out, minds, vmd, pts);
  hipLaunchKernelGGL(k_A, dim3(BB*28 + MU_KA), dim3(256), 0, stream, pts, minds, out, ad);
  hipLaunchKernelGGL(k_inv_m, dim3(BB + MU_IV), dim3(256), 0, stream, ad, vmd, pts, out);
}